// Round 9
// baseline (683.361 us; speedup 1.0000x reference)
//
#include <hip/hip_runtime.h>
#include <hip/hip_bf16.h>

#define NG   1000
#define NPG  50
#define EPG  600
#define NE   600000
#define NN   50000
#define DD   128
#define H2   256
#define KEEP 300

typedef __attribute__((ext_vector_type(8))) short bf16x8;
typedef __attribute__((ext_vector_type(4))) float f32x4;

// ---------- bf16 helpers ----------

__device__ __forceinline__ unsigned short bfb(float x) {
  __hip_bfloat16 h = __float2bfloat16(x);
  union { __hip_bfloat16 h; unsigned short u; } cv; cv.h = h; return cv.u;
}
__device__ __forceinline__ float ubfs(unsigned short u) {
  union { unsigned u; float f; } c; c.u = ((unsigned)u) << 16; return c.f;
}
__device__ __forceinline__ unsigned pk2(float a, float b) {
  return (unsigned)bfb(a) | ((unsigned)bfb(b) << 16);
}
__device__ __forceinline__ float ubf_lo(unsigned u) {
  union { unsigned u; float f; } c; c.u = u << 16; return c.f;
}
__device__ __forceinline__ float ubf_hi(unsigned u) {
  union { unsigned u; float f; } c; c.u = u & 0xffff0000u; return c.f;
}
__device__ __forceinline__ void split2(float x, unsigned short& h, unsigned short& l) {
  h = bfb(x);
  l = bfb(x - ubfs(h));
}
__device__ __forceinline__ void split_pk(float a, float b, unsigned& ph, unsigned& pl) {
  unsigned short ha, la, hb, lb;
  split2(a, ha, la); split2(b, hb, lb);
  ph = (unsigned)ha | ((unsigned)hb << 16);
  pl = (unsigned)la | ((unsigned)lb << 16);
}

// swizzled u32 index into a [64][64]-u32 row-major tile
__device__ __forceinline__ int zb_word(int r, int f2) {
  return (r << 6) + (f2 ^ ((r & 7) << 2));
}

// ---------- shared memory structs ----------

struct __align__(16) S1 {                // k1 (split precision, 512 threads)
  unsigned Z[8192];                      // 32 KB: Zh=[0..4095], Zl=[4096..8191];
                                         //        doubles as T-hi [64r][128 u32] and f32 M tile
  unsigned Tl[8192];                     // 32 KB: T-lo [64r][128 u32]
  float red[64][8];                      //  2 KB (8 waves)
  float stats[64][2];
  unsigned short erow[EPG];
  unsigned short ecol[EPG];
  unsigned short adj[EPG];
  int offs[NPG + 1];
  int deg[NPG];
};                                       // ~71 KB -> 2 blocks/CU

struct __align__(16) Smem3 {             // k3 (round-2/3 config restored)
  unsigned Zb[64 * 64];
  unsigned Tr[64 * 32];
  float red[64][4];
  float stats[64][2];
  unsigned short erow[EPG];
  unsigned short ecol[EPG];
  unsigned short adj[EPG];
  int offs[NPG + 1];
  int deg[NPG];
  float s[EPG];
  float key[EPG];
  float cw[EPG];
  float mask[64];
  float cnt;
};

// ---------- CSR build ----------

template <int NT, typename SM>
__device__ __forceinline__ void build_csr(SM& sm, int tid, const int* __restrict__ EI, int g) {
  for (int e = tid; e < EPG; e += NT) {
    int re = EI[g * EPG + e] - g * NPG;
    int ce = EI[NE + g * EPG + e] - g * NPG;
    sm.erow[e] = (unsigned short)re;
    sm.ecol[e] = (unsigned short)ce;
  }
  for (int i = tid; i < NPG; i += NT) sm.deg[i] = 0;
  __syncthreads();
  for (int e = tid; e < EPG; e += NT) atomicAdd(&sm.deg[sm.erow[e]], 1);
  __syncthreads();
  if (tid == 0) {
    sm.offs[0] = 0;
    for (int n = 0; n < NPG; n++) sm.offs[n + 1] = sm.offs[n] + sm.deg[n];
  }
  __syncthreads();
  if (tid < NPG) {
    int p = sm.offs[tid];
    for (int e = 0; e < EPG; e++) {
      if ((int)sm.erow[e] == tid) { sm.adj[p++] = (unsigned short)(((int)sm.ecol[e] << 10) | e); }
    }
  }
  __syncthreads();
}

// ---------- kernel 0: weight conversion ----------

__global__ __launch_bounds__(256) void k_wconv(
    const float* __restrict__ Wemb, const float* __restrict__ gW1, const float* __restrict__ gW2,
    const float* __restrict__ mW1, const float* __restrict__ mW2,
    const float* __restrict__ fW1, const float* __restrict__ fW2,
    unsigned short* __restrict__ fW1t, unsigned short* __restrict__ fW2t,
    unsigned short* __restrict__ eh, unsigned short* __restrict__ el,
    unsigned short* __restrict__ g1h, unsigned short* __restrict__ g1l,
    unsigned short* __restrict__ g2h, unsigned short* __restrict__ g2l,
    unsigned short* __restrict__ m1h, unsigned short* __restrict__ m1l,
    unsigned short* __restrict__ m2h, unsigned short* __restrict__ m2l) {
  const int idx = blockIdx.x * 256 + threadIdx.x;
  if (idx < 3 * H2 * DD) {
    const int l = idx / (H2 * DD), rem = idx % (H2 * DD);
    { const int c = rem >> 7, k = rem & 127; fW1t[idx] = bfb(fW1[l * H2 * DD + k * H2 + c]); }
    { const int j = rem >> 8, c2 = rem & 255; fW2t[idx] = bfb(fW2[l * H2 * DD + c2 * DD + j]); }
  }
  if (idx < DD * DD) {
    const int j = idx >> 7, k = idx & 127;
    split2(Wemb[k * DD + j], eh[idx], el[idx]);
  }
  if (idx < 2 * H2 * DD) {
    const int l = idx >> 15, rem = idx & 32767;
    const int c = rem >> 7, k = rem & 127;
    split2(gW1[l * H2 * DD + k * H2 + c], g1h[idx], g1l[idx]);
  }
  if (idx < 2 * H2 * DD) {
    const int l = idx >> 15, rem = idx & 32767;
    const int j = rem >> 8, c = rem & 255;
    split2(gW2[l * H2 * DD + c * DD + j], g2h[idx], g2l[idx]);
  }
  if (idx < H2 * DD) {
    const int c = idx >> 7, k = idx & 127;
    split2(mW1[k * H2 + c], m1h[idx], m1l[idx]);
  }
  if (idx < H2 * DD) {
    const int j = idx >> 8, c = idx & 255;
    split2(mW2[c * DD + j], m2h[idx], m2l[idx]);
  }
}

// ---------- k1: split-precision gather (512 threads: 8 row-groups) ----------

__device__ __forceinline__ void gather_s(S1& sm, int tid) {
  unsigned* ZH = sm.Z;
  unsigned* ZL = sm.Z + 4096;
  const int f2 = tid & 63, rg = tid >> 6;
  const int r0 = (rg < 2) ? rg * 7 : 14 + (rg - 2) * 6;
  const int rn = (rg < 2) ? 7 : 6;
  float a0[7], a1[7];
#pragma unroll
  for (int i = 0; i < 7; i++) {
    if (i < rn) {
      const int r = r0 + i;
      const int wd = zb_word(r, f2);
      const unsigned uh = ZH[wd], ul = ZL[wd];
      float x0 = ubf_lo(uh) + ubf_lo(ul), x1 = ubf_hi(uh) + ubf_hi(ul);
      const int p0 = sm.offs[r], p1 = sm.offs[r + 1];
      for (int p = p0; p < p1; p++) {
        const int cn = sm.adj[p] >> 10;
        const int wc = zb_word(cn, f2);
        const unsigned vh = ZH[wc], vl = ZL[wc];
        x0 += ubf_lo(vh) + ubf_lo(vl);
        x1 += ubf_hi(vh) + ubf_hi(vl);
      }
      a0[i] = x0; a1[i] = x1;
    }
  }
  __syncthreads();
#pragma unroll
  for (int i = 0; i < 7; i++) {
    if (i < rn) {
      const int wd = zb_word(r0 + i, f2);
      unsigned ph, pl;
      split_pk(a0[i], a1[i], ph, pl);
      ZH[wd] = ph; ZL[wd] = pl;
    }
  }
  __syncthreads();
}

// ---------- k1: embed GEMM 128->128 (8 waves x 16 j) ----------
// #pragma unroll 1 (round 9): definitive anti-hoisting test. Full unroll let the
// scheduler hoist all iterations' fragment loads -> spill at the 64-arch-VGPR
// budget. unroll 1 bounds live fragments to one iteration.

__device__ __forceinline__ void embed_mfma(S1& sm, int tid,
    const unsigned short* __restrict__ eh, const unsigned short* __restrict__ el,
    const float* __restrict__ bemb) {
  const int lane = tid & 63, w = tid >> 6, lg = lane >> 4, l15 = lane & 15;
  f32x4 acc[4];
#pragma unroll
  for (int nt = 0; nt < 4; nt++) acc[nt] = (f32x4){0.f, 0.f, 0.f, 0.f};

#pragma unroll 1
  for (int ks = 0; ks < 4; ks++) {
    const int koff = ks * 32 + lg * 8;
    bf16x8 ah, al;
    {
      const int j = w * 16 + l15;
      ah = *(const bf16x8*)(eh + j * DD + koff);
      al = *(const bf16x8*)(el + j * DD + koff);
    }
#pragma unroll
    for (int ntp = 0; ntp < 2; ntp++) {
      bf16x8 bh[2], bl[2];
#pragma unroll
      for (int q = 0; q < 2; q++) {
        const int r = l15 + (ntp * 2 + q) * 16;
        const int byte = (r << 8) + ((koff << 1) ^ ((r & 7) << 4));
        bh[q] = *(const bf16x8*)((const char*)sm.Z + byte);
        bl[q] = *(const bf16x8*)((const char*)sm.Z + 16384 + byte);
      }
#pragma unroll
      for (int q = 0; q < 2; q++) {
        const int nt = ntp * 2 + q;
        acc[nt] = __builtin_amdgcn_mfma_f32_16x16x32_bf16(ah, bh[q], acc[nt], 0, 0, 0);
        acc[nt] = __builtin_amdgcn_mfma_f32_16x16x32_bf16(al, bh[q], acc[nt], 0, 0, 0);
        acc[nt] = __builtin_amdgcn_mfma_f32_16x16x32_bf16(ah, bl[q], acc[nt], 0, 0, 0);
      }
    }
  }
  __syncthreads();
  {
    unsigned* ZH = sm.Z;
    unsigned* ZL = sm.Z + 4096;
    const int j0 = w * 16 + lg * 4;
    const float4 b4 = *(const float4*)(bemb + j0);
#pragma unroll
    for (int nt = 0; nt < 4; nt++) {
      const int r = l15 + nt * 16;
      const float v0 = acc[nt][0] + b4.x, v1 = acc[nt][1] + b4.y;
      const float v2 = acc[nt][2] + b4.z, v3 = acc[nt][3] + b4.w;
      unsigned h0, l0, h1, l1;
      split_pk(v0, v1, h0, l0); split_pk(v2, v3, h1, l1);
      const int wd = (r << 6) + ((j0 >> 1) ^ ((r & 7) << 2));
      *(uint2*)&ZH[wd] = make_uint2(h0, h1);
      *(uint2*)&ZL[wd] = make_uint2(l0, l1);
    }
  }
  __syncthreads();
}

// ---------- k1: split MLP, 8 waves, unroll-1 k-loops ----------
// Per-accumulator MFMA order identical to rounds 3-8 -> bit-identical numerics.

__device__ __forceinline__ void mlp1(S1& sm, int tid,
    const unsigned short* __restrict__ W1h, const unsigned short* __restrict__ W1l,
    const float* __restrict__ b1, const float* __restrict__ aw, const float* __restrict__ ab,
    const unsigned short* __restrict__ W2h, const unsigned short* __restrict__ W2l,
    const float* __restrict__ b2, const int fout) {
  const int lane = tid & 63, w = tid >> 6, lg = lane >> 4, l15 = lane & 15;
  const int wb = w * 32;

  // ---- GEMM1: M=256 c (8 waves x 32), N=64 r, K=128, 3-term split ----
  f32x4 acc[2][4];
#pragma unroll
  for (int mt = 0; mt < 2; mt++)
#pragma unroll
    for (int nt = 0; nt < 4; nt++) acc[mt][nt] = (f32x4){0.f, 0.f, 0.f, 0.f};

#pragma unroll 1
  for (int ks = 0; ks < 4; ks++) {
    const int koff = ks * 32 + lg * 8;
    bf16x8 ah[2], al[2];
#pragma unroll
    for (int mt = 0; mt < 2; mt++) {
      const int c = wb + mt * 16 + l15;
      ah[mt] = *(const bf16x8*)(W1h + c * DD + koff);
      al[mt] = *(const bf16x8*)(W1l + c * DD + koff);
    }
#pragma unroll
    for (int ntp = 0; ntp < 2; ntp++) {
      bf16x8 bh[2], bl[2];
#pragma unroll
      for (int q = 0; q < 2; q++) {
        const int r = l15 + (ntp * 2 + q) * 16;
        const int byte = (r << 8) + ((koff << 1) ^ ((r & 7) << 4));
        bh[q] = *(const bf16x8*)((const char*)sm.Z + byte);
        bl[q] = *(const bf16x8*)((const char*)sm.Z + 16384 + byte);
      }
#pragma unroll
      for (int mt = 0; mt < 2; mt++)
#pragma unroll
        for (int q = 0; q < 2; q++) {
          const int nt = ntp * 2 + q;
          acc[mt][nt] = __builtin_amdgcn_mfma_f32_16x16x32_bf16(ah[mt], bh[q], acc[mt][nt], 0, 0, 0);
          acc[mt][nt] = __builtin_amdgcn_mfma_f32_16x16x32_bf16(al[mt], bh[q], acc[mt][nt], 0, 0, 0);
          acc[mt][nt] = __builtin_amdgcn_mfma_f32_16x16x32_bf16(ah[mt], bl[q], acc[mt][nt], 0, 0, 0);
        }
    }
  }
  // + b1
#pragma unroll
  for (int mt = 0; mt < 2; mt++) {
    const float4 b4 = *(const float4*)(b1 + wb + mt * 16 + lg * 4);
#pragma unroll
    for (int nt = 0; nt < 4; nt++) {
      acc[mt][nt][0] += b4.x; acc[mt][nt][1] += b4.y;
      acc[mt][nt][2] += b4.z; acc[mt][nt][3] += b4.w;
    }
  }
  // ---- norm stats over c(=256) per r ----
#pragma unroll
  for (int nt = 0; nt < 4; nt++) {
    float s = 0.f;
#pragma unroll
    for (int mt = 0; mt < 2; mt++)
      s += acc[mt][nt][0] + acc[mt][nt][1] + acc[mt][nt][2] + acc[mt][nt][3];
    s += __shfl_xor(s, 16, 64); s += __shfl_xor(s, 32, 64);
    if (lg == 0) sm.red[l15 + nt * 16][w] = s;
  }
  __syncthreads();      // all GEMM1 LDS reads complete past this point
  if (tid < 64) {
    float t = 0.f;
#pragma unroll
    for (int q = 0; q < 8; q++) t += sm.red[tid][q];
    sm.stats[tid][0] = t * (1.f / H2);
  }
  __syncthreads();
#pragma unroll
  for (int nt = 0; nt < 4; nt++) {
    const float mu = sm.stats[l15 + nt * 16][0];
    float s = 0.f;
#pragma unroll
    for (int mt = 0; mt < 2; mt++)
#pragma unroll
      for (int q = 0; q < 4; q++) { const float d = acc[mt][nt][q] - mu; s += d * d; }
    s += __shfl_xor(s, 16, 64); s += __shfl_xor(s, 32, 64);
    if (lg == 0) sm.red[l15 + nt * 16][w] = s;
  }
  __syncthreads();
  if (tid < 64) {
    float t = 0.f;
#pragma unroll
    for (int q = 0; q < 8; q++) t += sm.red[tid][q];
    sm.stats[tid][1] = 1.0f / sqrtf(t * (1.f / H2) + 1e-5f);
  }
  __syncthreads();

  // ---- affine + relu + split: write full T (overwrites Z; GEMM1 inputs dead) ----
  {
    unsigned* thi = sm.Z;
#pragma unroll
    for (int nt = 0; nt < 4; nt++) {
      const int r = l15 + nt * 16;
      const float mu = sm.stats[r][0], rs = sm.stats[r][1];
#pragma unroll
      for (int mt = 0; mt < 2; mt++) {
        const float4 aw4 = *(const float4*)(aw + wb + mt * 16 + lg * 4);
        const float4 ab4 = *(const float4*)(ab + wb + mt * 16 + lg * 4);
        const float t0 = fmaxf(aw4.x * (acc[mt][nt][0] - mu) * rs + ab4.x, 0.f);
        const float t1 = fmaxf(aw4.y * (acc[mt][nt][1] - mu) * rs + ab4.y, 0.f);
        const float t2 = fmaxf(aw4.z * (acc[mt][nt][2] - mu) * rs + ab4.z, 0.f);
        const float t3 = fmaxf(aw4.w * (acc[mt][nt][3] - mu) * rs + ab4.w, 0.f);
        unsigned h0, l0, h1, l1;
        split_pk(t0, t1, h0, l0); split_pk(t2, t3, h1, l1);
        const int c2w = w * 16 + mt * 8 + lg * 2;           // u32 col (c>>1)
        const int wd = (r << 7) + (c2w ^ ((r & 7) << 2));
        *(uint2*)&thi[wd] = make_uint2(h0, h1);
        *(uint2*)&sm.Tl[wd] = make_uint2(l0, l1);
      }
    }
  }
  __syncthreads();

  // ---- GEMM2: M=128 j (8 waves x 16), N=64 r, K=256 flat in 8 steps of 32 ----
  f32x4 acc2[4];
#pragma unroll
  for (int nt = 0; nt < 4; nt++) acc2[nt] = (f32x4){0.f, 0.f, 0.f, 0.f};

  {
    const unsigned* thi = sm.Z;
#pragma unroll 1
    for (int kk = 0; kk < 8; kk++) {
      const int cs = kk * 16 + lg * 4;                      // u32 col base
      const int cglob = kk * 32 + lg * 8;
      const int j = w * 16 + l15;
      const bf16x8 wh = *(const bf16x8*)(W2h + j * H2 + cglob);
      const bf16x8 wl = *(const bf16x8*)(W2l + j * H2 + cglob);
#pragma unroll
      for (int ntp = 0; ntp < 2; ntp++) {
        bf16x8 th[2], tl[2];
#pragma unroll
        for (int q = 0; q < 2; q++) {
          const int r = l15 + (ntp * 2 + q) * 16;
          const int wd = (r << 7) + (cs ^ ((r & 7) << 2));
          th[q] = *(const bf16x8*)&thi[wd];
          tl[q] = *(const bf16x8*)&sm.Tl[wd];
        }
#pragma unroll
        for (int q = 0; q < 2; q++) {
          const int nt = ntp * 2 + q;
          acc2[nt] = __builtin_amdgcn_mfma_f32_16x16x32_bf16(wh, th[q], acc2[nt], 0, 0, 0);
          acc2[nt] = __builtin_amdgcn_mfma_f32_16x16x32_bf16(wl, th[q], acc2[nt], 0, 0, 0);
          acc2[nt] = __builtin_amdgcn_mfma_f32_16x16x32_bf16(wh, tl[q], acc2[nt], 0, 0, 0);
        }
      }
    }
  }

  __syncthreads();                                          // T reads done before Z overwrite
  unsigned* ZH = sm.Z;
  unsigned* ZL = sm.Z + 4096;
  const int j0 = w * 16 + lg * 4;
  const float4 b4 = *(const float4*)(b2 + j0);
  if (!fout) {
#pragma unroll
    for (int nt = 0; nt < 4; nt++) {
      const int r = l15 + nt * 16;
      const float v0 = acc2[nt][0] + b4.x, v1 = acc2[nt][1] + b4.y;
      const float v2 = acc2[nt][2] + b4.z, v3 = acc2[nt][3] + b4.w;
      unsigned h0, l0, h1, l1;
      split_pk(v0, v1, h0, l0); split_pk(v2, v3, h1, l1);
      const int wd = (r << 6) + ((j0 >> 1) ^ ((r & 7) << 2));
      *(uint2*)&ZH[wd] = make_uint2(h0, h1);
      *(uint2*)&ZL[wd] = make_uint2(l0, l1);
    }
  } else {
    float* M = (float*)sm.Z;  // 32 KB = 64 rows x 128 f32
    const int k0 = j0 >> 2;
#pragma unroll
    for (int nt = 0; nt < 4; nt++) {
      const int r = l15 + nt * 16;
      *(float4*)&M[(r << 7) + ((k0 ^ (r & 7)) << 2)] =
          make_float4(acc2[nt][0] + b4.x, acc2[nt][1] + b4.y,
                      acc2[nt][2] + b4.z, acc2[nt][3] + b4.w);
    }
  }
  __syncthreads();
}

// ---------- kernel 1 (512 threads): embed + 2 GIN + rep + mean-encoder + scores ----------

__global__ __launch_bounds__(512, 4) void k1_gnn_score(
    const float* __restrict__ x, const int* __restrict__ EI,
    const unsigned short* __restrict__ eh, const unsigned short* __restrict__ el,
    const float* __restrict__ bemb,
    const unsigned short* __restrict__ g1h, const unsigned short* __restrict__ g1l,
    const float* __restrict__ gb1, const float* __restrict__ gaw, const float* __restrict__ gab,
    const unsigned short* __restrict__ g2h, const unsigned short* __restrict__ g2l,
    const float* __restrict__ gb2,
    const unsigned short* __restrict__ m1h, const unsigned short* __restrict__ m1l,
    const float* __restrict__ mb1, const float* __restrict__ maw, const float* __restrict__ mab,
    const unsigned short* __restrict__ m2h, const unsigned short* __restrict__ m2l,
    const float* __restrict__ mb2,
    unsigned* __restrict__ repb, float* __restrict__ esc, float* __restrict__ gmm) {
  __shared__ S1 sm;
  const int g = blockIdx.x, tid = threadIdx.x;
  unsigned* ZH = sm.Z;
  unsigned* ZL = sm.Z + 4096;

  for (int idx = tid; idx < 64 * 64; idx += 512) {
    const int r = idx >> 6, f2 = idx & 63;
    float x0 = 0.f, x1 = 0.f;
    if (r < NPG) {
      const float2 v = *(const float2*)&x[(size_t)(g * NPG + r) * DD + 2 * f2];
      x0 = v.x; x1 = v.y;
    }
    unsigned ph, pl;
    split_pk(x0, x1, ph, pl);
    const int wd = zb_word(r, f2);
    ZH[wd] = ph; ZL[wd] = pl;
  }
  build_csr<512>(sm, tid, EI, g);

  embed_mfma(sm, tid, eh, el, bemb);

  for (int l = 0; l < 2; l++) {
    gather_s(sm, tid);
    mlp1(sm, tid, g1h + l * H2 * DD, g1l + l * H2 * DD, gb1 + l * H2, gaw + l * H2, gab + l * H2,
         g2h + l * H2 * DD, g2l + l * H2 * DD, gb2 + l * DD, 0);
  }
  for (int idx = tid; idx < NPG * 64; idx += 512) {
    const int r = idx >> 6, f2 = idx & 63;
    repb[(size_t)(g * NPG + r) * 64 + f2] = ZH[zb_word(r, f2)];
  }
  mlp1(sm, tid, m1h, m1l, mb1, maw, mab, m2h, m2l, mb2, 1);

  const float* M = (const float*)sm.Z;
  float mn = 3.402823466e38f, mx = -3.402823466e38f;
  for (int e = tid; e < EPG; e += 512) {
    const int r = sm.erow[e], cn = sm.ecol[e];
    const int sr = (r & 7), sc = (cn & 7);
    float acc = 0.0f;
    for (int k0 = 0; k0 < 32; k0++) {
      const float4 a = *(const float4*)&M[(r << 7) + ((k0 ^ sr) << 2)];
      const float4 b = *(const float4*)&M[(cn << 7) + ((k0 ^ sc) << 2)];
      acc += a.x * b.x; acc += a.y * b.y; acc += a.z * b.z; acc += a.w * b.w;
    }
    const float scv = acc * (1.0f / DD);
    esc[g * EPG + e] = scv;
    mn = fminf(mn, scv); mx = fmaxf(mx, scv);
  }
#pragma unroll
  for (int m = 1; m < 64; m <<= 1) {
    mn = fminf(mn, __shfl_xor(mn, m, 64));
    mx = fmaxf(mx, __shfl_xor(mx, m, 64));
  }
  const int lane = tid & 63, wid = tid >> 6;
  if (lane == 0) { sm.red[0][wid] = mn; sm.red[1][wid] = mx; }
  __syncthreads();
  if (tid == 0) {
    float a = sm.red[0][0], b = sm.red[1][0];
#pragma unroll
    for (int q = 1; q < 8; q++) { a = fminf(a, sm.red[0][q]); b = fmaxf(b, sm.red[1][q]); }
    gmm[g] = a; gmm[NG + g] = b;
  }
}

// ---------- kernel 2: global min/max ----------

__global__ __launch_bounds__(256) void k2_minmax(const float* __restrict__ gmm,
                                                 float* __restrict__ smm) {
  __shared__ float ra[4], rb[4];
  const int tid = threadIdx.x;
  float mn = 3.402823466e38f, mx = -3.402823466e38f;
  for (int i = tid; i < NG; i += 256) {
    mn = fminf(mn, gmm[i]);
    mx = fmaxf(mx, gmm[NG + i]);
  }
#pragma unroll
  for (int m = 1; m < 64; m <<= 1) {
    mn = fminf(mn, __shfl_xor(mn, m, 64));
    mx = fmaxf(mx, __shfl_xor(mx, m, 64));
  }
  const int lane = tid & 63, wid = tid >> 6;
  if (lane == 0) { ra[wid] = mn; rb[wid] = mx; }
  __syncthreads();
  if (tid == 0) {
    smm[0] = fminf(fminf(ra[0], ra[1]), fminf(ra[2], ra[3]));
    smm[1] = fmaxf(fmaxf(rb[0], rb[1]), fmaxf(rb[2], rb[3]));
  }
}

// ---------- k3 (launch bound reverted to round-2/3 spill-free config) ----------

__device__ __forceinline__ void gather3(Smem3& sm, int tid) {
  const int f2 = tid & 63, rg = tid >> 6;
  const int r0 = (rg < 3) ? rg * 13 : 39;
  const int rn = (rg < 3) ? 13 : 11;
  float a0[13], a1[13];
#pragma unroll
  for (int i = 0; i < 13; i++) {
    if (i < rn) {
      const int r = r0 + i;
      const unsigned u = sm.Zb[zb_word(r, f2)];
      float x0 = ubf_lo(u), x1 = ubf_hi(u);
      const int p0 = sm.offs[r], p1 = sm.offs[r + 1];
      for (int p = p0; p < p1; p++) {
        const int ad = sm.adj[p];
        const int cn = ad >> 10;
        const float wg = sm.cw[ad & 1023];
        const unsigned v = sm.Zb[zb_word(cn, f2)];
        x0 = fmaf(wg, ubf_lo(v), x0);
        x1 = fmaf(wg, ubf_hi(v), x1);
      }
      a0[i] = x0; a1[i] = x1;
    }
  }
  __syncthreads();
#pragma unroll
  for (int i = 0; i < 13; i++) {
    if (i < rn) sm.Zb[zb_word(r0 + i, f2)] = pk2(a0[i], a1[i]);
  }
  __syncthreads();
}

__device__ __forceinline__ void fe_mlp(Smem3& sm, int tid,
    const unsigned short* __restrict__ W1t, const unsigned short* __restrict__ W2t,
    const float* __restrict__ b1, const float* __restrict__ aw, const float* __restrict__ ab,
    const float* __restrict__ b2, float* __restrict__ outp) {
  const int lane = tid & 63, w = tid >> 6, lg = lane >> 4, l15 = lane & 15;
  const int wb = w * 64;

  f32x4 acc[4][4];
#pragma unroll
  for (int mt = 0; mt < 4; mt++)
#pragma unroll
    for (int nt = 0; nt < 4; nt++) acc[mt][nt] = (f32x4){0.f, 0.f, 0.f, 0.f};

#pragma unroll
  for (int ks = 0; ks < 4; ks++) {
    const int koff = ks * 32 + lg * 8;
    bf16x8 bfr[4], afr[4];
#pragma unroll
    for (int nt = 0; nt < 4; nt++) {
      const int r = l15 + nt * 16;
      const int byte = (r << 8) + ((koff << 1) ^ ((r & 7) << 4));
      bfr[nt] = *(const bf16x8*)((const char*)sm.Zb + byte);
    }
#pragma unroll
    for (int mt = 0; mt < 4; mt++) {
      const int c = wb + mt * 16 + l15;
      afr[mt] = *(const bf16x8*)(W1t + c * 128 + koff);
    }
#pragma unroll
    for (int mt = 0; mt < 4; mt++)
#pragma unroll
      for (int nt = 0; nt < 4; nt++)
        acc[mt][nt] = __builtin_amdgcn_mfma_f32_16x16x32_bf16(afr[mt], bfr[nt], acc[mt][nt], 0, 0, 0);
  }
#pragma unroll
  for (int mt = 0; mt < 4; mt++) {
    const float4 b4 = *(const float4*)(b1 + wb + mt * 16 + lg * 4);
#pragma unroll
    for (int nt = 0; nt < 4; nt++) {
      acc[mt][nt][0] += b4.x; acc[mt][nt][1] += b4.y;
      acc[mt][nt][2] += b4.z; acc[mt][nt][3] += b4.w;
    }
  }
#pragma unroll
  for (int nt = 0; nt < 4; nt++) {
    float s = 0.f;
#pragma unroll
    for (int mt = 0; mt < 4; mt++)
      s += acc[mt][nt][0] + acc[mt][nt][1] + acc[mt][nt][2] + acc[mt][nt][3];
    s += __shfl_xor(s, 16, 64); s += __shfl_xor(s, 32, 64);
    if (lg == 0) sm.red[l15 + nt * 16][w] = s;
  }
  __syncthreads();
  if (tid < 64)
    sm.stats[tid][0] = (sm.red[tid][0] + sm.red[tid][1] + sm.red[tid][2] + sm.red[tid][3]) * (1.f / H2);
  __syncthreads();
#pragma unroll
  for (int nt = 0; nt < 4; nt++) {
    const float mu = sm.stats[l15 + nt * 16][0];
    float s = 0.f;
#pragma unroll
    for (int mt = 0; mt < 4; mt++)
#pragma unroll
      for (int q = 0; q < 4; q++) { const float d = acc[mt][nt][q] - mu; s += d * d; }
    s += __shfl_xor(s, 16, 64); s += __shfl_xor(s, 32, 64);
    if (lg == 0) sm.red[l15 + nt * 16][w] = s;
  }
  __syncthreads();
  if (tid < 64) {
    const float var = (sm.red[tid][0] + sm.red[tid][1] + sm.red[tid][2] + sm.red[tid][3]) * (1.f / H2);
    sm.stats[tid][1] = 1.0f / sqrtf(var + 1e-5f);
  }
  __syncthreads();
  unsigned pk[4][4][2];
#pragma unroll
  for (int nt = 0; nt < 4; nt++) {
    const int r = l15 + nt * 16;
    const float mu = sm.stats[r][0], rs = sm.stats[r][1];
#pragma unroll
    for (int mt = 0; mt < 4; mt++) {
      const float4 aw4 = *(const float4*)(aw + wb + mt * 16 + lg * 4);
      const float4 ab4 = *(const float4*)(ab + wb + mt * 16 + lg * 4);
      const float t0 = fmaxf(aw4.x * (acc[mt][nt][0] - mu) * rs + ab4.x, 0.f);
      const float t1 = fmaxf(aw4.y * (acc[mt][nt][1] - mu) * rs + ab4.y, 0.f);
      const float t2 = fmaxf(aw4.z * (acc[mt][nt][2] - mu) * rs + ab4.z, 0.f);
      const float t3 = fmaxf(aw4.w * (acc[mt][nt][3] - mu) * rs + ab4.w, 0.f);
      pk[nt][mt][0] = pk2(t0, t1);
      pk[nt][mt][1] = pk2(t2, t3);
    }
  }
  f32x4 acc2[2][4];
#pragma unroll
  for (int mt = 0; mt < 2; mt++)
#pragma unroll
    for (int nt = 0; nt < 4; nt++) acc2[mt][nt] = (f32x4){0.f, 0.f, 0.f, 0.f};

  for (int ch = 0; ch < 4; ch++) {
    __syncthreads();
    if (w == ch) {
#pragma unroll
      for (int nt = 0; nt < 4; nt++) {
        const int r = l15 + nt * 16;
#pragma unroll
        for (int mt = 0; mt < 4; mt++) {
          const int cl2 = 8 * mt + 2 * lg;
          const int wd = (r << 5) + (cl2 ^ ((r & 7) << 2));
          *(uint2*)&sm.Tr[wd] = make_uint2(pk[nt][mt][0], pk[nt][mt][1]);
        }
      }
    }
    __syncthreads();
#pragma unroll
    for (int ks = 0; ks < 2; ks++) {
      const int klocal = ks * 32 + lg * 8;
      bf16x8 bfr[4], afr[2];
#pragma unroll
      for (int nt = 0; nt < 4; nt++) {
        const int r = l15 + nt * 16;
        const int byte = (r << 7) + ((klocal << 1) ^ ((r & 7) << 4));
        bfr[nt] = *(const bf16x8*)((const char*)sm.Tr + byte);
      }
      const int cglob = ch * 64 + klocal;
#pragma unroll
      for (int mt = 0; mt < 2; mt++) {
        const int j = w * 32 + mt * 16 + l15;
        afr[mt] = *(const bf16x8*)(W2t + j * 256 + cglob);
      }
#pragma unroll
      for (int mt = 0; mt < 2; mt++)
#pragma unroll
        for (int nt = 0; nt < 4; nt++)
          acc2[mt][nt] = __builtin_amdgcn_mfma_f32_16x16x32_bf16(afr[mt], bfr[nt], acc2[mt][nt], 0, 0, 0);
    }
  }

  if (outp == nullptr) {
    __syncthreads();
#pragma unroll
    for (int mt = 0; mt < 2; mt++) {
      const float4 b4 = *(const float4*)(b2 + w * 32 + mt * 16 + lg * 4);
#pragma unroll
      for (int nt = 0; nt < 4; nt++) {
        const int r = l15 + nt * 16;
        if (r < NPG) {
          const float v0 = acc2[mt][nt][0] + b4.x, v1 = acc2[mt][nt][1] + b4.y;
          const float v2 = acc2[mt][nt][2] + b4.z, v3 = acc2[mt][nt][3] + b4.w;
          const int f2 = (w * 32 + mt * 16 + lg * 4) >> 1;
          const int wd = (r << 6) + (f2 ^ ((r & 7) << 2));
          *(uint2*)&sm.Zb[wd] = make_uint2(pk2(v0, v1), pk2(v2, v3));
        }
      }
    }
    __syncthreads();
  } else {
#pragma unroll
    for (int mt = 0; mt < 2; mt++) {
      const float4 b4 = *(const float4*)(b2 + w * 32 + mt * 16 + lg * 4);
      float s0 = 0.f, s1 = 0.f, s2 = 0.f, s3 = 0.f;
#pragma unroll
      for (int nt = 0; nt < 4; nt++) {
        const int r = l15 + nt * 16;
        const float m = sm.mask[r];
        s0 = fmaf(m, acc2[mt][nt][0] + b4.x, s0);
        s1 = fmaf(m, acc2[mt][nt][1] + b4.y, s1);
        s2 = fmaf(m, acc2[mt][nt][2] + b4.z, s2);
        s3 = fmaf(m, acc2[mt][nt][3] + b4.w, s3);
      }
#pragma unroll
      for (int msk = 1; msk < 16; msk <<= 1) {
        s0 += __shfl_xor(s0, msk, 64); s1 += __shfl_xor(s1, msk, 64);
        s2 += __shfl_xor(s2, msk, 64); s3 += __shfl_xor(s3, msk, 64);
      }
      if (l15 == 0) {
        const float ic = 1.0f / sm.cnt;
        const int j0 = w * 32 + mt * 16 + lg * 4;
        *(float4*)(outp + j0) = make_float4(s0 * ic, s1 * ic, s2 * ic, s3 * ic);
      }
    }
  }
}

__global__ __launch_bounds__(256, 3) void k3_select_fe(
    const int* __restrict__ EI,
    const unsigned short* __restrict__ W1t, const unsigned short* __restrict__ W2t,
    const float* __restrict__ fb1, const float* __restrict__ faw,
    const float* __restrict__ fab, const float* __restrict__ fb2,
    const unsigned* __restrict__ repb, const float* __restrict__ esc,
    const float* __restrict__ smm, float* __restrict__ out) {
  __shared__ Smem3 sm;
  const int g = blockIdx.x, tid = threadIdx.x;

  build_csr<256>(sm, tid, EI, g);

  const float smin = smm[0], smax = smm[1];
  const float denom = (smax - smin) + 1e-12f;
  for (int e = tid; e < EPG; e += 256) {
    const float sc = esc[g * EPG + e];
    sm.s[e] = sc;
    sm.key[e] = (sc - smin) / denom - (float)g;
  }
  for (int i = tid; i < 64; i += 256) sm.mask[i] = 0.0f;
  for (int idx = tid; idx < 64 * 64; idx += 256) {
    const int r = idx >> 6, f2 = idx & 63;
    unsigned p = 0u;
    if (r < NPG) p = repb[(size_t)(g * NPG + r) * 64 + f2];
    sm.Zb[zb_word(r, f2)] = p;
  }
  __syncthreads();

  for (int e = tid; e < EPG; e += 256) {
    const float ki = sm.key[e];
    int cntk = 0;
    for (int j2 = 0; j2 < EPG; j2++) {
      const float kj = sm.key[j2];
      cntk += ((kj > ki) || ((kj == ki) && (j2 < e))) ? 1 : 0;
    }
    const bool kept = cntk < KEEP;
    sm.cw[e] = kept ? sm.s[e] : 0.0f;
    if (kept) {
      sm.mask[sm.erow[e]] = 1.0f;
      sm.mask[sm.ecol[e]] = 1.0f;
    }
  }
  __syncthreads();
  if (tid == 0) {
    float cc = 0.f;
    for (int r = 0; r < NPG; r++) cc += sm.mask[r];
    sm.cnt = fmaxf(cc, 1.0f);
  }
  __syncthreads();

  for (int l = 0; l < 3; l++) {
    gather3(sm, tid);
    fe_mlp(sm, tid, W1t + l * H2 * DD, W2t + l * H2 * DD,
           fb1 + l * H2, faw + l * H2, fab + l * H2, fb2 + l * DD,
           (l == 2) ? (out + (size_t)g * DD) : nullptr);
  }
}

// ---------- launch ----------

extern "C" void kernel_launch(void* const* d_in, const int* in_sizes, int n_in,
                              void* d_out, int out_size, void* d_ws, size_t ws_size,
                              hipStream_t stream) {
  (void)in_sizes; (void)n_in; (void)out_size; (void)ws_size;
  const float* x    = (const float*)d_in[0];
  const int*   EI   = (const int*)d_in[1];
  const float* Wemb = (const float*)d_in[3];
  const float* bemb = (const float*)d_in[4];
  const float* gW1  = (const float*)d_in[5];
  const float* gb1  = (const float*)d_in[6];
  const float* gaw  = (const float*)d_in[7];
  const float* gab  = (const float*)d_in[8];
  const float* gW2  = (const float*)d_in[9];
  const float* gb2  = (const float*)d_in[10];
  const float* mW1  = (const float*)d_in[11];
  const float* mb1  = (const float*)d_in[12];
  const float* maw  = (const float*)d_in[13];
  const float* mab  = (const float*)d_in[14];
  const float* mW2  = (const float*)d_in[15];
  const float* mb2  = (const float*)d_in[16];
  const float* fW1  = (const float*)d_in[17];
  const float* fb1  = (const float*)d_in[18];
  const float* faw  = (const float*)d_in[19];
  const float* fab  = (const float*)d_in[20];
  const float* fW2  = (const float*)d_in[21];
  const float* fb2  = (const float*)d_in[22];

  unsigned short* p = (unsigned short*)d_ws;
  unsigned short* fW1t = p; p += 3 * H2 * DD;
  unsigned short* fW2t = p; p += 3 * H2 * DD;
  unsigned short* eh   = p; p += DD * DD;
  unsigned short* el   = p; p += DD * DD;
  unsigned short* g1h  = p; p += 2 * H2 * DD;
  unsigned short* g1l  = p; p += 2 * H2 * DD;
  unsigned short* g2h  = p; p += 2 * H2 * DD;
  unsigned short* g2l  = p; p += 2 * H2 * DD;
  unsigned short* m1h  = p; p += H2 * DD;
  unsigned short* m1l  = p; p += H2 * DD;
  unsigned short* m2h  = p; p += H2 * DD;
  unsigned short* m2l  = p; p += H2 * DD;
  unsigned* repb = (unsigned*)p;
  float* esc = (float*)(repb + (size_t)NN * 64);
  float* gmm = esc + NE;
  float* smm = gmm + 2 * NG;
  float* out = (float*)d_out;

  k_wconv<<<(3 * H2 * DD + 255) / 256, 256, 0, stream>>>(
      Wemb, gW1, gW2, mW1, mW2, fW1, fW2,
      fW1t, fW2t, eh, el, g1h, g1l, g2h, g2l, m1h, m1l, m2h, m2l);
  k1_gnn_score<<<NG, 512, 0, stream>>>(x, EI, eh, el, bemb,
                                       g1h, g1l, gb1, gaw, gab, g2h, g2l, gb2,
                                       m1h, m1l, mb1, maw, mab, m2h, m2l, mb2,
                                       repb, esc, gmm);
  k2_minmax<<<1, 256, 0, stream>>>(gmm, smm);
  k3_select_fe<<<NG, 256, 0, stream>>>(EI, fW1t, fW2t, fb1, faw, fab, fb2, repb, esc, smm, out);
}

// Round 10
// 639.251 us; speedup vs baseline: 1.0690x; 1.0690x over previous
//
#include <hip/hip_runtime.h>
#include <hip/hip_bf16.h>

#define NG   1000
#define NPG  50
#define EPG  600
#define NE   600000
#define NN   50000
#define DD   128
#define H2   256
#define KEEP 300

typedef __attribute__((ext_vector_type(8))) short bf16x8;
typedef __attribute__((ext_vector_type(4))) float f32x4;

// ---------- bf16 helpers ----------

__device__ __forceinline__ unsigned short bfb(float x) {
  __hip_bfloat16 h = __float2bfloat16(x);
  union { __hip_bfloat16 h; unsigned short u; } cv; cv.h = h; return cv.u;
}
__device__ __forceinline__ float ubfs(unsigned short u) {
  union { unsigned u; float f; } c; c.u = ((unsigned)u) << 16; return c.f;
}
__device__ __forceinline__ unsigned pk2(float a, float b) {
  return (unsigned)bfb(a) | ((unsigned)bfb(b) << 16);
}
__device__ __forceinline__ float ubf_lo(unsigned u) {
  union { unsigned u; float f; } c; c.u = u << 16; return c.f;
}
__device__ __forceinline__ float ubf_hi(unsigned u) {
  union { unsigned u; float f; } c; c.u = u & 0xffff0000u; return c.f;
}
__device__ __forceinline__ void split2(float x, unsigned short& h, unsigned short& l) {
  h = bfb(x);
  l = bfb(x - ubfs(h));
}
__device__ __forceinline__ void split_pk(float a, float b, unsigned& ph, unsigned& pl) {
  unsigned short ha, la, hb, lb;
  split2(a, ha, la); split2(b, hb, lb);
  ph = (unsigned)ha | ((unsigned)hb << 16);
  pl = (unsigned)la | ((unsigned)lb << 16);
}

// swizzled u32 index into a [64][64]-u32 row-major tile
__device__ __forceinline__ int zb_word(int r, int f2) {
  return (r << 6) + (f2 ^ ((r & 7) << 2));
}

// ---------- shared memory structs ----------

struct __align__(16) S1 {                // k1 (split precision, 512 threads)
  unsigned Z[8192];                      // 32 KB: Zh=[0..4095], Zl=[4096..8191];
                                         //        doubles as T-hi [64r][128 u32] and f32 M tile
  unsigned Tl[8192];                     // 32 KB: T-lo [64r][128 u32]
  float red[64][8];                      //  2 KB (8 waves)
  float stats[64][2];
  unsigned short erow[EPG];
  unsigned short ecol[EPG];
  unsigned short adj[EPG];
  int offs[NPG + 1];
  int deg[NPG];
};                                       // ~71 KB -> 2 blocks/CU

struct __align__(16) Smem3 {             // k3
  unsigned Zb[64 * 64];
  unsigned Tr[64 * 32];
  float red[64][4];
  float stats[64][2];
  unsigned short erow[EPG];
  unsigned short ecol[EPG];
  unsigned short adj[EPG];
  int offs[NPG + 1];
  int deg[NPG];
  float s[EPG];
  float key[EPG];
  float cw[EPG];
  float mask[64];
  float cnt;
};

// ---------- CSR build ----------

template <int NT, typename SM>
__device__ __forceinline__ void build_csr(SM& sm, int tid, const int* __restrict__ EI, int g) {
  for (int e = tid; e < EPG; e += NT) {
    int re = EI[g * EPG + e] - g * NPG;
    int ce = EI[NE + g * EPG + e] - g * NPG;
    sm.erow[e] = (unsigned short)re;
    sm.ecol[e] = (unsigned short)ce;
  }
  for (int i = tid; i < NPG; i += NT) sm.deg[i] = 0;
  __syncthreads();
  for (int e = tid; e < EPG; e += NT) atomicAdd(&sm.deg[sm.erow[e]], 1);
  __syncthreads();
  if (tid == 0) {
    sm.offs[0] = 0;
    for (int n = 0; n < NPG; n++) sm.offs[n + 1] = sm.offs[n] + sm.deg[n];
  }
  __syncthreads();
  if (tid < NPG) {
    int p = sm.offs[tid];
    for (int e = 0; e < EPG; e++) {
      if ((int)sm.erow[e] == tid) { sm.adj[p++] = (unsigned short)(((int)sm.ecol[e] << 10) | e); }
    }
  }
  __syncthreads();
}

// ---------- kernel 0: weight conversion ----------

__global__ __launch_bounds__(256) void k_wconv(
    const float* __restrict__ Wemb, const float* __restrict__ gW1, const float* __restrict__ gW2,
    const float* __restrict__ mW1, const float* __restrict__ mW2,
    const float* __restrict__ fW1, const float* __restrict__ fW2,
    unsigned short* __restrict__ fW1t, unsigned short* __restrict__ fW2t,
    unsigned short* __restrict__ eh, unsigned short* __restrict__ el,
    unsigned short* __restrict__ g1h, unsigned short* __restrict__ g1l,
    unsigned short* __restrict__ g2h, unsigned short* __restrict__ g2l,
    unsigned short* __restrict__ m1h, unsigned short* __restrict__ m1l,
    unsigned short* __restrict__ m2h, unsigned short* __restrict__ m2l) {
  const int idx = blockIdx.x * 256 + threadIdx.x;
  if (idx < 3 * H2 * DD) {
    const int l = idx / (H2 * DD), rem = idx % (H2 * DD);
    { const int c = rem >> 7, k = rem & 127; fW1t[idx] = bfb(fW1[l * H2 * DD + k * H2 + c]); }
    { const int j = rem >> 8, c2 = rem & 255; fW2t[idx] = bfb(fW2[l * H2 * DD + c2 * DD + j]); }
  }
  if (idx < DD * DD) {
    const int j = idx >> 7, k = idx & 127;
    split2(Wemb[k * DD + j], eh[idx], el[idx]);
  }
  if (idx < 2 * H2 * DD) {
    const int l = idx >> 15, rem = idx & 32767;
    const int c = rem >> 7, k = rem & 127;
    split2(gW1[l * H2 * DD + k * H2 + c], g1h[idx], g1l[idx]);
  }
  if (idx < 2 * H2 * DD) {
    const int l = idx >> 15, rem = idx & 32767;
    const int j = rem >> 8, c = rem & 255;
    split2(gW2[l * H2 * DD + c * DD + j], g2h[idx], g2l[idx]);
  }
  if (idx < H2 * DD) {
    const int c = idx >> 7, k = idx & 127;
    split2(mW1[k * H2 + c], m1h[idx], m1l[idx]);
  }
  if (idx < H2 * DD) {
    const int j = idx >> 8, c = idx & 255;
    split2(mW2[c * DD + j], m2h[idx], m2l[idx]);
  }
}

// ---------- k1: split-precision gather (512 threads: 8 row-groups) ----------

__device__ __forceinline__ void gather_s(S1& sm, int tid) {
  unsigned* ZH = sm.Z;
  unsigned* ZL = sm.Z + 4096;
  const int f2 = tid & 63, rg = tid >> 6;
  const int r0 = (rg < 2) ? rg * 7 : 14 + (rg - 2) * 6;
  const int rn = (rg < 2) ? 7 : 6;
  float a0[7], a1[7];
#pragma unroll
  for (int i = 0; i < 7; i++) {
    if (i < rn) {
      const int r = r0 + i;
      const int wd = zb_word(r, f2);
      const unsigned uh = ZH[wd], ul = ZL[wd];
      float x0 = ubf_lo(uh) + ubf_lo(ul), x1 = ubf_hi(uh) + ubf_hi(ul);
      const int p0 = sm.offs[r], p1 = sm.offs[r + 1];
      for (int p = p0; p < p1; p++) {
        const int cn = sm.adj[p] >> 10;
        const int wc = zb_word(cn, f2);
        const unsigned vh = ZH[wc], vl = ZL[wc];
        x0 += ubf_lo(vh) + ubf_lo(vl);
        x1 += ubf_hi(vh) + ubf_hi(vl);
      }
      a0[i] = x0; a1[i] = x1;
    }
  }
  __syncthreads();
#pragma unroll
  for (int i = 0; i < 7; i++) {
    if (i < rn) {
      const int wd = zb_word(r0 + i, f2);
      unsigned ph, pl;
      split_pk(a0[i], a1[i], ph, pl);
      ZH[wd] = ph; ZL[wd] = pl;
    }
  }
  __syncthreads();
}

// ---------- k1: embed GEMM (unroll-1 k-loops; confirmed anti-hoisting fix) ----------

__device__ __forceinline__ void embed_mfma(S1& sm, int tid,
    const unsigned short* __restrict__ eh, const unsigned short* __restrict__ el,
    const float* __restrict__ bemb) {
  const int lane = tid & 63, w = tid >> 6, lg = lane >> 4, l15 = lane & 15;
  f32x4 acc[4];
#pragma unroll
  for (int nt = 0; nt < 4; nt++) acc[nt] = (f32x4){0.f, 0.f, 0.f, 0.f};

#pragma unroll 1
  for (int ks = 0; ks < 4; ks++) {
    const int koff = ks * 32 + lg * 8;
    bf16x8 ah, al;
    {
      const int j = w * 16 + l15;
      ah = *(const bf16x8*)(eh + j * DD + koff);
      al = *(const bf16x8*)(el + j * DD + koff);
    }
#pragma unroll
    for (int ntp = 0; ntp < 2; ntp++) {
      bf16x8 bh[2], bl[2];
#pragma unroll
      for (int q = 0; q < 2; q++) {
        const int r = l15 + (ntp * 2 + q) * 16;
        const int byte = (r << 8) + ((koff << 1) ^ ((r & 7) << 4));
        bh[q] = *(const bf16x8*)((const char*)sm.Z + byte);
        bl[q] = *(const bf16x8*)((const char*)sm.Z + 16384 + byte);
      }
#pragma unroll
      for (int q = 0; q < 2; q++) {
        const int nt = ntp * 2 + q;
        acc[nt] = __builtin_amdgcn_mfma_f32_16x16x32_bf16(ah, bh[q], acc[nt], 0, 0, 0);
        acc[nt] = __builtin_amdgcn_mfma_f32_16x16x32_bf16(al, bh[q], acc[nt], 0, 0, 0);
        acc[nt] = __builtin_amdgcn_mfma_f32_16x16x32_bf16(ah, bl[q], acc[nt], 0, 0, 0);
      }
    }
  }
  __syncthreads();
  {
    unsigned* ZH = sm.Z;
    unsigned* ZL = sm.Z + 4096;
    const int j0 = w * 16 + lg * 4;
    const float4 b4 = *(const float4*)(bemb + j0);
#pragma unroll
    for (int nt = 0; nt < 4; nt++) {
      const int r = l15 + nt * 16;
      const float v0 = acc[nt][0] + b4.x, v1 = acc[nt][1] + b4.y;
      const float v2 = acc[nt][2] + b4.z, v3 = acc[nt][3] + b4.w;
      unsigned h0, l0, h1, l1;
      split_pk(v0, v1, h0, l0); split_pk(v2, v3, h1, l1);
      const int wd = (r << 6) + ((j0 >> 1) ^ ((r & 7) << 2));
      *(uint2*)&ZH[wd] = make_uint2(h0, h1);
      *(uint2*)&ZL[wd] = make_uint2(l0, l1);
    }
  }
  __syncthreads();
}

// ---------- k1: split MLP, 8 waves, unroll-1 k-loops ----------

__device__ __forceinline__ void mlp1(S1& sm, int tid,
    const unsigned short* __restrict__ W1h, const unsigned short* __restrict__ W1l,
    const float* __restrict__ b1, const float* __restrict__ aw, const float* __restrict__ ab,
    const unsigned short* __restrict__ W2h, const unsigned short* __restrict__ W2l,
    const float* __restrict__ b2, const int fout) {
  const int lane = tid & 63, w = tid >> 6, lg = lane >> 4, l15 = lane & 15;
  const int wb = w * 32;

  // ---- GEMM1: M=256 c (8 waves x 32), N=64 r, K=128, 3-term split ----
  f32x4 acc[2][4];
#pragma unroll
  for (int mt = 0; mt < 2; mt++)
#pragma unroll
    for (int nt = 0; nt < 4; nt++) acc[mt][nt] = (f32x4){0.f, 0.f, 0.f, 0.f};

#pragma unroll 1
  for (int ks = 0; ks < 4; ks++) {
    const int koff = ks * 32 + lg * 8;
    bf16x8 ah[2], al[2];
#pragma unroll
    for (int mt = 0; mt < 2; mt++) {
      const int c = wb + mt * 16 + l15;
      ah[mt] = *(const bf16x8*)(W1h + c * DD + koff);
      al[mt] = *(const bf16x8*)(W1l + c * DD + koff);
    }
#pragma unroll
    for (int ntp = 0; ntp < 2; ntp++) {
      bf16x8 bh[2], bl[2];
#pragma unroll
      for (int q = 0; q < 2; q++) {
        const int r = l15 + (ntp * 2 + q) * 16;
        const int byte = (r << 8) + ((koff << 1) ^ ((r & 7) << 4));
        bh[q] = *(const bf16x8*)((const char*)sm.Z + byte);
        bl[q] = *(const bf16x8*)((const char*)sm.Z + 16384 + byte);
      }
#pragma unroll
      for (int mt = 0; mt < 2; mt++)
#pragma unroll
        for (int q = 0; q < 2; q++) {
          const int nt = ntp * 2 + q;
          acc[mt][nt] = __builtin_amdgcn_mfma_f32_16x16x32_bf16(ah[mt], bh[q], acc[mt][nt], 0, 0, 0);
          acc[mt][nt] = __builtin_amdgcn_mfma_f32_16x16x32_bf16(al[mt], bh[q], acc[mt][nt], 0, 0, 0);
          acc[mt][nt] = __builtin_amdgcn_mfma_f32_16x16x32_bf16(ah[mt], bl[q], acc[mt][nt], 0, 0, 0);
        }
    }
  }
  // + b1
#pragma unroll
  for (int mt = 0; mt < 2; mt++) {
    const float4 b4 = *(const float4*)(b1 + wb + mt * 16 + lg * 4);
#pragma unroll
    for (int nt = 0; nt < 4; nt++) {
      acc[mt][nt][0] += b4.x; acc[mt][nt][1] += b4.y;
      acc[mt][nt][2] += b4.z; acc[mt][nt][3] += b4.w;
    }
  }
  // ---- norm stats over c(=256) per r ----
#pragma unroll
  for (int nt = 0; nt < 4; nt++) {
    float s = 0.f;
#pragma unroll
    for (int mt = 0; mt < 2; mt++)
      s += acc[mt][nt][0] + acc[mt][nt][1] + acc[mt][nt][2] + acc[mt][nt][3];
    s += __shfl_xor(s, 16, 64); s += __shfl_xor(s, 32, 64);
    if (lg == 0) sm.red[l15 + nt * 16][w] = s;
  }
  __syncthreads();
  if (tid < 64) {
    float t = 0.f;
#pragma unroll
    for (int q = 0; q < 8; q++) t += sm.red[tid][q];
    sm.stats[tid][0] = t * (1.f / H2);
  }
  __syncthreads();
#pragma unroll
  for (int nt = 0; nt < 4; nt++) {
    const float mu = sm.stats[l15 + nt * 16][0];
    float s = 0.f;
#pragma unroll
    for (int mt = 0; mt < 2; mt++)
#pragma unroll
      for (int q = 0; q < 4; q++) { const float d = acc[mt][nt][q] - mu; s += d * d; }
    s += __shfl_xor(s, 16, 64); s += __shfl_xor(s, 32, 64);
    if (lg == 0) sm.red[l15 + nt * 16][w] = s;
  }
  __syncthreads();
  if (tid < 64) {
    float t = 0.f;
#pragma unroll
    for (int q = 0; q < 8; q++) t += sm.red[tid][q];
    sm.stats[tid][1] = 1.0f / sqrtf(t * (1.f / H2) + 1e-5f);
  }
  __syncthreads();

  // ---- affine + relu + split: write full T ----
  {
    unsigned* thi = sm.Z;
#pragma unroll
    for (int nt = 0; nt < 4; nt++) {
      const int r = l15 + nt * 16;
      const float mu = sm.stats[r][0], rs = sm.stats[r][1];
#pragma unroll
      for (int mt = 0; mt < 2; mt++) {
        const float4 aw4 = *(const float4*)(aw + wb + mt * 16 + lg * 4);
        const float4 ab4 = *(const float4*)(ab + wb + mt * 16 + lg * 4);
        const float t0 = fmaxf(aw4.x * (acc[mt][nt][0] - mu) * rs + ab4.x, 0.f);
        const float t1 = fmaxf(aw4.y * (acc[mt][nt][1] - mu) * rs + ab4.y, 0.f);
        const float t2 = fmaxf(aw4.z * (acc[mt][nt][2] - mu) * rs + ab4.z, 0.f);
        const float t3 = fmaxf(aw4.w * (acc[mt][nt][3] - mu) * rs + ab4.w, 0.f);
        unsigned h0, l0, h1, l1;
        split_pk(t0, t1, h0, l0); split_pk(t2, t3, h1, l1);
        const int c2w = w * 16 + mt * 8 + lg * 2;
        const int wd = (r << 7) + (c2w ^ ((r & 7) << 2));
        *(uint2*)&thi[wd] = make_uint2(h0, h1);
        *(uint2*)&sm.Tl[wd] = make_uint2(l0, l1);
      }
    }
  }
  __syncthreads();

  // ---- GEMM2: M=128 j (8 waves x 16), N=64 r, K=256 flat in 8 steps of 32 ----
  f32x4 acc2[4];
#pragma unroll
  for (int nt = 0; nt < 4; nt++) acc2[nt] = (f32x4){0.f, 0.f, 0.f, 0.f};

  {
    const unsigned* thi = sm.Z;
#pragma unroll 1
    for (int kk = 0; kk < 8; kk++) {
      const int cs = kk * 16 + lg * 4;
      const int cglob = kk * 32 + lg * 8;
      const int j = w * 16 + l15;
      const bf16x8 wh = *(const bf16x8*)(W2h + j * H2 + cglob);
      const bf16x8 wl = *(const bf16x8*)(W2l + j * H2 + cglob);
#pragma unroll
      for (int ntp = 0; ntp < 2; ntp++) {
        bf16x8 th[2], tl[2];
#pragma unroll
        for (int q = 0; q < 2; q++) {
          const int r = l15 + (ntp * 2 + q) * 16;
          const int wd = (r << 7) + (cs ^ ((r & 7) << 2));
          th[q] = *(const bf16x8*)&thi[wd];
          tl[q] = *(const bf16x8*)&sm.Tl[wd];
        }
#pragma unroll
        for (int q = 0; q < 2; q++) {
          const int nt = ntp * 2 + q;
          acc2[nt] = __builtin_amdgcn_mfma_f32_16x16x32_bf16(wh, th[q], acc2[nt], 0, 0, 0);
          acc2[nt] = __builtin_amdgcn_mfma_f32_16x16x32_bf16(wl, th[q], acc2[nt], 0, 0, 0);
          acc2[nt] = __builtin_amdgcn_mfma_f32_16x16x32_bf16(wh, tl[q], acc2[nt], 0, 0, 0);
        }
      }
    }
  }

  __syncthreads();
  unsigned* ZH = sm.Z;
  unsigned* ZL = sm.Z + 4096;
  const int j0 = w * 16 + lg * 4;
  const float4 b4 = *(const float4*)(b2 + j0);
  if (!fout) {
#pragma unroll
    for (int nt = 0; nt < 4; nt++) {
      const int r = l15 + nt * 16;
      const float v0 = acc2[nt][0] + b4.x, v1 = acc2[nt][1] + b4.y;
      const float v2 = acc2[nt][2] + b4.z, v3 = acc2[nt][3] + b4.w;
      unsigned h0, l0, h1, l1;
      split_pk(v0, v1, h0, l0); split_pk(v2, v3, h1, l1);
      const int wd = (r << 6) + ((j0 >> 1) ^ ((r & 7) << 2));
      *(uint2*)&ZH[wd] = make_uint2(h0, h1);
      *(uint2*)&ZL[wd] = make_uint2(l0, l1);
    }
  } else {
    float* M = (float*)sm.Z;
    const int k0 = j0 >> 2;
#pragma unroll
    for (int nt = 0; nt < 4; nt++) {
      const int r = l15 + nt * 16;
      *(float4*)&M[(r << 7) + ((k0 ^ (r & 7)) << 2)] =
          make_float4(acc2[nt][0] + b4.x, acc2[nt][1] + b4.y,
                      acc2[nt][2] + b4.z, acc2[nt][3] + b4.w);
    }
  }
  __syncthreads();
}

// ---------- kernel 1 (512 threads) ----------

__global__ __launch_bounds__(512, 4) void k1_gnn_score(
    const float* __restrict__ x, const int* __restrict__ EI,
    const unsigned short* __restrict__ eh, const unsigned short* __restrict__ el,
    const float* __restrict__ bemb,
    const unsigned short* __restrict__ g1h, const unsigned short* __restrict__ g1l,
    const float* __restrict__ gb1, const float* __restrict__ gaw, const float* __restrict__ gab,
    const unsigned short* __restrict__ g2h, const unsigned short* __restrict__ g2l,
    const float* __restrict__ gb2,
    const unsigned short* __restrict__ m1h, const unsigned short* __restrict__ m1l,
    const float* __restrict__ mb1, const float* __restrict__ maw, const float* __restrict__ mab,
    const unsigned short* __restrict__ m2h, const unsigned short* __restrict__ m2l,
    const float* __restrict__ mb2,
    unsigned* __restrict__ repb, float* __restrict__ esc, float* __restrict__ gmm) {
  __shared__ S1 sm;
  const int g = blockIdx.x, tid = threadIdx.x;
  unsigned* ZH = sm.Z;
  unsigned* ZL = sm.Z + 4096;

  for (int idx = tid; idx < 64 * 64; idx += 512) {
    const int r = idx >> 6, f2 = idx & 63;
    float x0 = 0.f, x1 = 0.f;
    if (r < NPG) {
      const float2 v = *(const float2*)&x[(size_t)(g * NPG + r) * DD + 2 * f2];
      x0 = v.x; x1 = v.y;
    }
    unsigned ph, pl;
    split_pk(x0, x1, ph, pl);
    const int wd = zb_word(r, f2);
    ZH[wd] = ph; ZL[wd] = pl;
  }
  build_csr<512>(sm, tid, EI, g);

  embed_mfma(sm, tid, eh, el, bemb);

  for (int l = 0; l < 2; l++) {
    gather_s(sm, tid);
    mlp1(sm, tid, g1h + l * H2 * DD, g1l + l * H2 * DD, gb1 + l * H2, gaw + l * H2, gab + l * H2,
         g2h + l * H2 * DD, g2l + l * H2 * DD, gb2 + l * DD, 0);
  }
  for (int idx = tid; idx < NPG * 64; idx += 512) {
    const int r = idx >> 6, f2 = idx & 63;
    repb[(size_t)(g * NPG + r) * 64 + f2] = ZH[zb_word(r, f2)];
  }
  mlp1(sm, tid, m1h, m1l, mb1, maw, mab, m2h, m2l, mb2, 1);

  const float* M = (const float*)sm.Z;
  float mn = 3.402823466e38f, mx = -3.402823466e38f;
  for (int e = tid; e < EPG; e += 512) {
    const int r = sm.erow[e], cn = sm.ecol[e];
    const int sr = (r & 7), sc = (cn & 7);
    float acc = 0.0f;
    for (int k0 = 0; k0 < 32; k0++) {
      const float4 a = *(const float4*)&M[(r << 7) + ((k0 ^ sr) << 2)];
      const float4 b = *(const float4*)&M[(cn << 7) + ((k0 ^ sc) << 2)];
      acc += a.x * b.x; acc += a.y * b.y; acc += a.z * b.z; acc += a.w * b.w;
    }
    const float scv = acc * (1.0f / DD);
    esc[g * EPG + e] = scv;
    mn = fminf(mn, scv); mx = fmaxf(mx, scv);
  }
#pragma unroll
  for (int m = 1; m < 64; m <<= 1) {
    mn = fminf(mn, __shfl_xor(mn, m, 64));
    mx = fmaxf(mx, __shfl_xor(mx, m, 64));
  }
  const int lane = tid & 63, wid = tid >> 6;
  if (lane == 0) { sm.red[0][wid] = mn; sm.red[1][wid] = mx; }
  __syncthreads();
  if (tid == 0) {
    float a = sm.red[0][0], b = sm.red[1][0];
#pragma unroll
    for (int q = 1; q < 8; q++) { a = fminf(a, sm.red[0][q]); b = fmaxf(b, sm.red[1][q]); }
    gmm[g] = a; gmm[NG + g] = b;
  }
}

// ---------- kernel 2: global min/max ----------

__global__ __launch_bounds__(256) void k2_minmax(const float* __restrict__ gmm,
                                                 float* __restrict__ smm) {
  __shared__ float ra[4], rb[4];
  const int tid = threadIdx.x;
  float mn = 3.402823466e38f, mx = -3.402823466e38f;
  for (int i = tid; i < NG; i += 256) {
    mn = fminf(mn, gmm[i]);
    mx = fmaxf(mx, gmm[NG + i]);
  }
#pragma unroll
  for (int m = 1; m < 64; m <<= 1) {
    mn = fminf(mn, __shfl_xor(mn, m, 64));
    mx = fmaxf(mx, __shfl_xor(mx, m, 64));
  }
  const int lane = tid & 63, wid = tid >> 6;
  if (lane == 0) { ra[wid] = mn; rb[wid] = mx; }
  __syncthreads();
  if (tid == 0) {
    smm[0] = fminf(fminf(ra[0], ra[1]), fminf(ra[2], ra[3]));
    smm[1] = fmaxf(fmaxf(rb[0], rb[1]), fmaxf(rb[2], rb[3]));
  }
}

// ---------- k3: gather (unchanged) ----------

__device__ __forceinline__ void gather3(Smem3& sm, int tid) {
  const int f2 = tid & 63, rg = tid >> 6;
  const int r0 = (rg < 3) ? rg * 13 : 39;
  const int rn = (rg < 3) ? 13 : 11;
  float a0[13], a1[13];
#pragma unroll
  for (int i = 0; i < 13; i++) {
    if (i < rn) {
      const int r = r0 + i;
      const unsigned u = sm.Zb[zb_word(r, f2)];
      float x0 = ubf_lo(u), x1 = ubf_hi(u);
      const int p0 = sm.offs[r], p1 = sm.offs[r + 1];
      for (int p = p0; p < p1; p++) {
        const int ad = sm.adj[p];
        const int cn = ad >> 10;
        const float wg = sm.cw[ad & 1023];
        const unsigned v = sm.Zb[zb_word(cn, f2)];
        x0 = fmaf(wg, ubf_lo(v), x0);
        x1 = fmaf(wg, ubf_hi(v), x1);
      }
      a0[i] = x0; a1[i] = x1;
    }
  }
  __syncthreads();
#pragma unroll
  for (int i = 0; i < 13; i++) {
    if (i < rn) sm.Zb[zb_word(r0 + i, f2)] = pk2(a0[i], a1[i]);
  }
  __syncthreads();
}

// ---------- k3: fe_mlp (round 10: unroll-1 loops; pk array removed — affine
// computed at staging turn; same per-element op sequence -> identical numerics) ----------

__device__ __forceinline__ void fe_mlp(Smem3& sm, int tid,
    const unsigned short* __restrict__ W1t, const unsigned short* __restrict__ W2t,
    const float* __restrict__ b1, const float* __restrict__ aw, const float* __restrict__ ab,
    const float* __restrict__ b2, float* __restrict__ outp) {
  const int lane = tid & 63, w = tid >> 6, lg = lane >> 4, l15 = lane & 15;
  const int wb = w * 64;

  f32x4 acc[4][4];
#pragma unroll
  for (int mt = 0; mt < 4; mt++)
#pragma unroll
    for (int nt = 0; nt < 4; nt++) acc[mt][nt] = (f32x4){0.f, 0.f, 0.f, 0.f};

#pragma unroll 1
  for (int ks = 0; ks < 4; ks++) {
    const int koff = ks * 32 + lg * 8;
    bf16x8 bfr[4], afr[4];
#pragma unroll
    for (int nt = 0; nt < 4; nt++) {
      const int r = l15 + nt * 16;
      const int byte = (r << 8) + ((koff << 1) ^ ((r & 7) << 4));
      bfr[nt] = *(const bf16x8*)((const char*)sm.Zb + byte);
    }
#pragma unroll
    for (int mt = 0; mt < 4; mt++) {
      const int c = wb + mt * 16 + l15;
      afr[mt] = *(const bf16x8*)(W1t + c * 128 + koff);
    }
#pragma unroll
    for (int mt = 0; mt < 4; mt++)
#pragma unroll
      for (int nt = 0; nt < 4; nt++)
        acc[mt][nt] = __builtin_amdgcn_mfma_f32_16x16x32_bf16(afr[mt], bfr[nt], acc[mt][nt], 0, 0, 0);
  }
#pragma unroll
  for (int mt = 0; mt < 4; mt++) {
    const float4 b4 = *(const float4*)(b1 + wb + mt * 16 + lg * 4);
#pragma unroll
    for (int nt = 0; nt < 4; nt++) {
      acc[mt][nt][0] += b4.x; acc[mt][nt][1] += b4.y;
      acc[mt][nt][2] += b4.z; acc[mt][nt][3] += b4.w;
    }
  }
#pragma unroll
  for (int nt = 0; nt < 4; nt++) {
    float s = 0.f;
#pragma unroll
    for (int mt = 0; mt < 4; mt++)
      s += acc[mt][nt][0] + acc[mt][nt][1] + acc[mt][nt][2] + acc[mt][nt][3];
    s += __shfl_xor(s, 16, 64); s += __shfl_xor(s, 32, 64);
    if (lg == 0) sm.red[l15 + nt * 16][w] = s;
  }
  __syncthreads();
  if (tid < 64)
    sm.stats[tid][0] = (sm.red[tid][0] + sm.red[tid][1] + sm.red[tid][2] + sm.red[tid][3]) * (1.f / H2);
  __syncthreads();
#pragma unroll
  for (int nt = 0; nt < 4; nt++) {
    const float mu = sm.stats[l15 + nt * 16][0];
    float s = 0.f;
#pragma unroll
    for (int mt = 0; mt < 4; mt++)
#pragma unroll
      for (int q = 0; q < 4; q++) { const float d = acc[mt][nt][q] - mu; s += d * d; }
    s += __shfl_xor(s, 16, 64); s += __shfl_xor(s, 32, 64);
    if (lg == 0) sm.red[l15 + nt * 16][w] = s;
  }
  __syncthreads();
  if (tid < 64) {
    const float var = (sm.red[tid][0] + sm.red[tid][1] + sm.red[tid][2] + sm.red[tid][3]) * (1.f / H2);
    sm.stats[tid][1] = 1.0f / sqrtf(var + 1e-5f);
  }
  __syncthreads();

  f32x4 acc2[2][4];
#pragma unroll
  for (int mt = 0; mt < 2; mt++)
#pragma unroll
    for (int nt = 0; nt < 4; nt++) acc2[mt][nt] = (f32x4){0.f, 0.f, 0.f, 0.f};

#pragma unroll 1
  for (int ch = 0; ch < 4; ch++) {
    __syncthreads();
    if (w == ch) {  // stage my 64-c chunk: affine+relu+split computed here (no pk array)
#pragma unroll
      for (int nt = 0; nt < 4; nt++) {
        const int r = l15 + nt * 16;
        const float mu = sm.stats[r][0], rs = sm.stats[r][1];
#pragma unroll
        for (int mt = 0; mt < 4; mt++) {
          const float4 aw4 = *(const float4*)(aw + wb + mt * 16 + lg * 4);
          const float4 ab4 = *(const float4*)(ab + wb + mt * 16 + lg * 4);
          const float t0 = fmaxf(aw4.x * (acc[mt][nt][0] - mu) * rs + ab4.x, 0.f);
          const float t1 = fmaxf(aw4.y * (acc[mt][nt][1] - mu) * rs + ab4.y, 0.f);
          const float t2 = fmaxf(aw4.z * (acc[mt][nt][2] - mu) * rs + ab4.z, 0.f);
          const float t3 = fmaxf(aw4.w * (acc[mt][nt][3] - mu) * rs + ab4.w, 0.f);
          const int cl2 = 8 * mt + 2 * lg;
          const int wd = (r << 5) + (cl2 ^ ((r & 7) << 2));
          *(uint2*)&sm.Tr[wd] = make_uint2(pk2(t0, t1), pk2(t2, t3));
        }
      }
    }
    __syncthreads();
#pragma unroll 1
    for (int ks = 0; ks < 2; ks++) {
      const int klocal = ks * 32 + lg * 8;
      bf16x8 bfr[4], afr[2];
#pragma unroll
      for (int nt = 0; nt < 4; nt++) {
        const int r = l15 + nt * 16;
        const int byte = (r << 7) + ((klocal << 1) ^ ((r & 7) << 4));
        bfr[nt] = *(const bf16x8*)((const char*)sm.Tr + byte);
      }
      const int cglob = ch * 64 + klocal;
#pragma unroll
      for (int mt = 0; mt < 2; mt++) {
        const int j = w * 32 + mt * 16 + l15;
        afr[mt] = *(const bf16x8*)(W2t + j * 256 + cglob);
      }
#pragma unroll
      for (int mt = 0; mt < 2; mt++)
#pragma unroll
        for (int nt = 0; nt < 4; nt++)
          acc2[mt][nt] = __builtin_amdgcn_mfma_f32_16x16x32_bf16(afr[mt], bfr[nt], acc2[mt][nt], 0, 0, 0);
    }
  }

  if (outp == nullptr) {
    __syncthreads();
#pragma unroll
    for (int mt = 0; mt < 2; mt++) {
      const float4 b4 = *(const float4*)(b2 + w * 32 + mt * 16 + lg * 4);
#pragma unroll
      for (int nt = 0; nt < 4; nt++) {
        const int r = l15 + nt * 16;
        if (r < NPG) {
          const float v0 = acc2[mt][nt][0] + b4.x, v1 = acc2[mt][nt][1] + b4.y;
          const float v2 = acc2[mt][nt][2] + b4.z, v3 = acc2[mt][nt][3] + b4.w;
          const int f2 = (w * 32 + mt * 16 + lg * 4) >> 1;
          const int wd = (r << 6) + (f2 ^ ((r & 7) << 2));
          *(uint2*)&sm.Zb[wd] = make_uint2(pk2(v0, v1), pk2(v2, v3));
        }
      }
    }
    __syncthreads();
  } else {
#pragma unroll
    for (int mt = 0; mt < 2; mt++) {
      const float4 b4 = *(const float4*)(b2 + w * 32 + mt * 16 + lg * 4);
      float s0 = 0.f, s1 = 0.f, s2 = 0.f, s3 = 0.f;
#pragma unroll
      for (int nt = 0; nt < 4; nt++) {
        const int r = l15 + nt * 16;
        const float m = sm.mask[r];
        s0 = fmaf(m, acc2[mt][nt][0] + b4.x, s0);
        s1 = fmaf(m, acc2[mt][nt][1] + b4.y, s1);
        s2 = fmaf(m, acc2[mt][nt][2] + b4.z, s2);
        s3 = fmaf(m, acc2[mt][nt][3] + b4.w, s3);
      }
#pragma unroll
      for (int msk = 1; msk < 16; msk <<= 1) {
        s0 += __shfl_xor(s0, msk, 64); s1 += __shfl_xor(s1, msk, 64);
        s2 += __shfl_xor(s2, msk, 64); s3 += __shfl_xor(s3, msk, 64);
      }
      if (l15 == 0) {
        const float ic = 1.0f / sm.cnt;
        const int j0 = w * 32 + mt * 16 + lg * 4;
        *(float4*)(outp + j0) = make_float4(s0 * ic, s1 * ic, s2 * ic, s3 * ic);
      }
    }
  }
}

__global__ __launch_bounds__(256, 4) void k3_select_fe(
    const int* __restrict__ EI,
    const unsigned short* __restrict__ W1t, const unsigned short* __restrict__ W2t,
    const float* __restrict__ fb1, const float* __restrict__ faw,
    const float* __restrict__ fab, const float* __restrict__ fb2,
    const unsigned* __restrict__ repb, const float* __restrict__ esc,
    const float* __restrict__ smm, float* __restrict__ out) {
  __shared__ Smem3 sm;
  const int g = blockIdx.x, tid = threadIdx.x;

  build_csr<256>(sm, tid, EI, g);

  const float smin = smm[0], smax = smm[1];
  const float denom = (smax - smin) + 1e-12f;
  for (int e = tid; e < EPG; e += 256) {
    const float sc = esc[g * EPG + e];
    sm.s[e] = sc;
    sm.key[e] = (sc - smin) / denom - (float)g;
  }
  for (int i = tid; i < 64; i += 256) sm.mask[i] = 0.0f;
  for (int idx = tid; idx < 64 * 64; idx += 256) {
    const int r = idx >> 6, f2 = idx & 63;
    unsigned p = 0u;
    if (r < NPG) p = repb[(size_t)(g * NPG + r) * 64 + f2];
    sm.Zb[zb_word(r, f2)] = p;
  }
  __syncthreads();

  for (int e = tid; e < EPG; e += 256) {
    const float ki = sm.key[e];
    int cntk = 0;
    for (int j2 = 0; j2 < EPG; j2++) {
      const float kj = sm.key[j2];
      cntk += ((kj > ki) || ((kj == ki) && (j2 < e))) ? 1 : 0;
    }
    const bool kept = cntk < KEEP;
    sm.cw[e] = kept ? sm.s[e] : 0.0f;
    if (kept) {
      sm.mask[sm.erow[e]] = 1.0f;
      sm.mask[sm.ecol[e]] = 1.0f;
    }
  }
  __syncthreads();
  if (tid == 0) {
    float cc = 0.f;
    for (int r = 0; r < NPG; r++) cc += sm.mask[r];
    sm.cnt = fmaxf(cc, 1.0f);
  }
  __syncthreads();

  for (int l = 0; l < 3; l++) {
    gather3(sm, tid);
    fe_mlp(sm, tid, W1t + l * H2 * DD, W2t + l * H2 * DD,
           fb1 + l * H2, faw + l * H2, fab + l * H2, fb2 + l * DD,
           (l == 2) ? (out + (size_t)g * DD) : nullptr);
  }
}

// ---------- launch ----------

extern "C" void kernel_launch(void* const* d_in, const int* in_sizes, int n_in,
                              void* d_out, int out_size, void* d_ws, size_t ws_size,
                              hipStream_t stream) {
  (void)in_sizes; (void)n_in; (void)out_size; (void)ws_size;
  const float* x    = (const float*)d_in[0];
  const int*   EI   = (const int*)d_in[1];
  const float* Wemb = (const float*)d_in[3];
  const float* bemb = (const float*)d_in[4];
  const float* gW1  = (const float*)d_in[5];
  const float* gb1  = (const float*)d_in[6];
  const float* gaw  = (const float*)d_in[7];
  const float* gab  = (const float*)d_in[8];
  const float* gW2  = (const float*)d_in[9];
  const float* gb2  = (const float*)d_in[10];
  const float* mW1  = (const float*)d_in[11];
  const float* mb1  = (const float*)d_in[12];
  const float* maw  = (const float*)d_in[13];
  const float* mab  = (const float*)d_in[14];
  const float* mW2  = (const float*)d_in[15];
  const float* mb2  = (const float*)d_in[16];
  const float* fW1  = (const float*)d_in[17];
  const float* fb1  = (const float*)d_in[18];
  const float* faw  = (const float*)d_in[19];
  const float* fab  = (const float*)d_in[20];
  const float* fW2  = (const float*)d_in[21];
  const float* fb2  = (const float*)d_in[22];

  unsigned short* p = (unsigned short*)d_ws;
  unsigned short* fW1t = p; p += 3 * H2 * DD;
  unsigned short* fW2t = p; p += 3 * H2 * DD;
  unsigned short* eh   = p; p += DD * DD;
  unsigned short* el   = p; p += DD * DD;
  unsigned short* g1h  = p; p += 2 * H2 * DD;
  unsigned short* g1l  = p; p += 2 * H2 * DD;
  unsigned short* g2h  = p; p += 2 * H2 * DD;
  unsigned short* g2l  = p; p += 2 * H2 * DD;
  unsigned short* m1h  = p; p += H2 * DD;
  unsigned short* m1l  = p; p += H2 * DD;
  unsigned short* m2h  = p; p += H2 * DD;
  unsigned short* m2l  = p; p += H2 * DD;
  unsigned* repb = (unsigned*)p;
  float* esc = (float*)(repb + (size_t)NN * 64);
  float* gmm = esc + NE;
  float* smm = gmm + 2 * NG;
  float* out = (float*)d_out;

  k_wconv<<<(3 * H2 * DD + 255) / 256, 256, 0, stream>>>(
      Wemb, gW1, gW2, mW1, mW2, fW1, fW2,
      fW1t, fW2t, eh, el, g1h, g1l, g2h, g2l, m1h, m1l, m2h, m2l);
  k1_gnn_score<<<NG, 512, 0, stream>>>(x, EI, eh, el, bemb,
                                       g1h, g1l, gb1, gaw, gab, g2h, g2l, gb2,
                                       m1h, m1l, mb1, maw, mab, m2h, m2l, mb2,
                                       repb, esc, gmm);
  k2_minmax<<<1, 256, 0, stream>>>(gmm, smm);
  k3_select_fe<<<NG, 256, 0, stream>>>(EI, fW1t, fW2t, fb1, faw, fab, fb2, repb, esc, smm, out);
}

// Round 11
// 594.144 us; speedup vs baseline: 1.1502x; 1.0759x over previous
//
#include <hip/hip_runtime.h>
#include <hip/hip_bf16.h>

#define NG   1000
#define NPG  50
#define EPG  600
#define NE   600000
#define NN   50000
#define DD   128
#define H2   256
#define KEEP 300

typedef __attribute__((ext_vector_type(8))) short bf16x8;
typedef __attribute__((ext_vector_type(4))) float f32x4;

// ---------- bf16 helpers ----------

__device__ __forceinline__ unsigned short bfb(float x) {
  __hip_bfloat16 h = __float2bfloat16(x);
  union { __hip_bfloat16 h; unsigned short u; } cv; cv.h = h; return cv.u;
}
__device__ __forceinline__ float ubfs(unsigned short u) {
  union { unsigned u; float f; } c; c.u = ((unsigned)u) << 16; return c.f;
}
__device__ __forceinline__ unsigned pk2(float a, float b) {
  return (unsigned)bfb(a) | ((unsigned)bfb(b) << 16);
}
__device__ __forceinline__ float ubf_lo(unsigned u) {
  union { unsigned u; float f; } c; c.u = u << 16; return c.f;
}
__device__ __forceinline__ float ubf_hi(unsigned u) {
  union { unsigned u; float f; } c; c.u = u & 0xffff0000u; return c.f;
}
__device__ __forceinline__ void split2(float x, unsigned short& h, unsigned short& l) {
  h = bfb(x);
  l = bfb(x - ubfs(h));
}
__device__ __forceinline__ void split_pk(float a, float b, unsigned& ph, unsigned& pl) {
  unsigned short ha, la, hb, lb;
  split2(a, ha, la); split2(b, hb, lb);
  ph = (unsigned)ha | ((unsigned)hb << 16);
  pl = (unsigned)la | ((unsigned)lb << 16);
}

// swizzled u32 index into a [64][64]-u32 row-major tile
__device__ __forceinline__ int zb_word(int r, int f2) {
  return (r << 6) + (f2 ^ ((r & 7) << 2));
}

// ---------- shared memory structs ----------

struct __align__(16) S1 {                // k1 (split precision, 512 threads)
  unsigned Z[8192];                      // 32 KB: Zh / Zl; doubles as T-hi and f32 M tile
  unsigned Tl[8192];                     // 32 KB: T-lo
  float red[64][8];
  float stats[64][2];
  unsigned short erow[EPG];
  unsigned short ecol[EPG];
  unsigned short adj[EPG];
  int offs[NPG + 1];
  int deg[NPG];
};                                       // ~71 KB -> 2 blocks/CU

struct __align__(16) Smem3 {             // k3 (512 threads, write-full-T structure)
  unsigned Zb[4096];                     // 16 KB activations (bf16 pairs, swizzled)
  unsigned T[8192];                      // 32 KB full T (64r x 128 u32, swizzled)
  float red[64][8];                      //  2 KB (8 waves)
  float stats[64][2];
  unsigned short erow[EPG];
  unsigned short ecol[EPG];
  unsigned short adj[EPG];
  int offs[NPG + 1];
  int deg[NPG];
  float s[EPG];
  float key[EPG];
  float cw[EPG];
  float mask[64];
  float cnt;
};                                       // ~62.4 KB -> 2 blocks/CU (16 waves/CU)

// ---------- CSR build ----------

template <int NT, typename SM>
__device__ __forceinline__ void build_csr(SM& sm, int tid, const int* __restrict__ EI, int g) {
  for (int e = tid; e < EPG; e += NT) {
    int re = EI[g * EPG + e] - g * NPG;
    int ce = EI[NE + g * EPG + e] - g * NPG;
    sm.erow[e] = (unsigned short)re;
    sm.ecol[e] = (unsigned short)ce;
  }
  for (int i = tid; i < NPG; i += NT) sm.deg[i] = 0;
  __syncthreads();
  for (int e = tid; e < EPG; e += NT) atomicAdd(&sm.deg[sm.erow[e]], 1);
  __syncthreads();
  if (tid == 0) {
    sm.offs[0] = 0;
    for (int n = 0; n < NPG; n++) sm.offs[n + 1] = sm.offs[n] + sm.deg[n];
  }
  __syncthreads();
  if (tid < NPG) {
    int p = sm.offs[tid];
    for (int e = 0; e < EPG; e++) {
      if ((int)sm.erow[e] == tid) { sm.adj[p++] = (unsigned short)(((int)sm.ecol[e] << 10) | e); }
    }
  }
  __syncthreads();
}

// ---------- kernel 0: weight conversion ----------

__global__ __launch_bounds__(256) void k_wconv(
    const float* __restrict__ Wemb, const float* __restrict__ gW1, const float* __restrict__ gW2,
    const float* __restrict__ mW1, const float* __restrict__ mW2,
    const float* __restrict__ fW1, const float* __restrict__ fW2,
    unsigned short* __restrict__ fW1t, unsigned short* __restrict__ fW2t,
    unsigned short* __restrict__ eh, unsigned short* __restrict__ el,
    unsigned short* __restrict__ g1h, unsigned short* __restrict__ g1l,
    unsigned short* __restrict__ g2h, unsigned short* __restrict__ g2l,
    unsigned short* __restrict__ m1h, unsigned short* __restrict__ m1l,
    unsigned short* __restrict__ m2h, unsigned short* __restrict__ m2l) {
  const int idx = blockIdx.x * 256 + threadIdx.x;
  if (idx < 3 * H2 * DD) {
    const int l = idx / (H2 * DD), rem = idx % (H2 * DD);
    { const int c = rem >> 7, k = rem & 127; fW1t[idx] = bfb(fW1[l * H2 * DD + k * H2 + c]); }
    { const int j = rem >> 8, c2 = rem & 255; fW2t[idx] = bfb(fW2[l * H2 * DD + c2 * DD + j]); }
  }
  if (idx < DD * DD) {
    const int j = idx >> 7, k = idx & 127;
    split2(Wemb[k * DD + j], eh[idx], el[idx]);
  }
  if (idx < 2 * H2 * DD) {
    const int l = idx >> 15, rem = idx & 32767;
    const int c = rem >> 7, k = rem & 127;
    split2(gW1[l * H2 * DD + k * H2 + c], g1h[idx], g1l[idx]);
  }
  if (idx < 2 * H2 * DD) {
    const int l = idx >> 15, rem = idx & 32767;
    const int j = rem >> 8, c = rem & 255;
    split2(gW2[l * H2 * DD + c * DD + j], g2h[idx], g2l[idx]);
  }
  if (idx < H2 * DD) {
    const int c = idx >> 7, k = idx & 127;
    split2(mW1[k * H2 + c], m1h[idx], m1l[idx]);
  }
  if (idx < H2 * DD) {
    const int j = idx >> 8, c = idx & 255;
    split2(mW2[c * DD + j], m2h[idx], m2l[idx]);
  }
}

// ---------- k1 (unchanged from round 10) ----------

__device__ __forceinline__ void gather_s(S1& sm, int tid) {
  unsigned* ZH = sm.Z;
  unsigned* ZL = sm.Z + 4096;
  const int f2 = tid & 63, rg = tid >> 6;
  const int r0 = (rg < 2) ? rg * 7 : 14 + (rg - 2) * 6;
  const int rn = (rg < 2) ? 7 : 6;
  float a0[7], a1[7];
#pragma unroll
  for (int i = 0; i < 7; i++) {
    if (i < rn) {
      const int r = r0 + i;
      const int wd = zb_word(r, f2);
      const unsigned uh = ZH[wd], ul = ZL[wd];
      float x0 = ubf_lo(uh) + ubf_lo(ul), x1 = ubf_hi(uh) + ubf_hi(ul);
      const int p0 = sm.offs[r], p1 = sm.offs[r + 1];
      for (int p = p0; p < p1; p++) {
        const int cn = sm.adj[p] >> 10;
        const int wc = zb_word(cn, f2);
        const unsigned vh = ZH[wc], vl = ZL[wc];
        x0 += ubf_lo(vh) + ubf_lo(vl);
        x1 += ubf_hi(vh) + ubf_hi(vl);
      }
      a0[i] = x0; a1[i] = x1;
    }
  }
  __syncthreads();
#pragma unroll
  for (int i = 0; i < 7; i++) {
    if (i < rn) {
      const int wd = zb_word(r0 + i, f2);
      unsigned ph, pl;
      split_pk(a0[i], a1[i], ph, pl);
      ZH[wd] = ph; ZL[wd] = pl;
    }
  }
  __syncthreads();
}

__device__ __forceinline__ void embed_mfma(S1& sm, int tid,
    const unsigned short* __restrict__ eh, const unsigned short* __restrict__ el,
    const float* __restrict__ bemb) {
  const int lane = tid & 63, w = tid >> 6, lg = lane >> 4, l15 = lane & 15;
  f32x4 acc[4];
#pragma unroll
  for (int nt = 0; nt < 4; nt++) acc[nt] = (f32x4){0.f, 0.f, 0.f, 0.f};

#pragma unroll 1
  for (int ks = 0; ks < 4; ks++) {
    const int koff = ks * 32 + lg * 8;
    bf16x8 ah, al;
    {
      const int j = w * 16 + l15;
      ah = *(const bf16x8*)(eh + j * DD + koff);
      al = *(const bf16x8*)(el + j * DD + koff);
    }
#pragma unroll
    for (int ntp = 0; ntp < 2; ntp++) {
      bf16x8 bh[2], bl[2];
#pragma unroll
      for (int q = 0; q < 2; q++) {
        const int r = l15 + (ntp * 2 + q) * 16;
        const int byte = (r << 8) + ((koff << 1) ^ ((r & 7) << 4));
        bh[q] = *(const bf16x8*)((const char*)sm.Z + byte);
        bl[q] = *(const bf16x8*)((const char*)sm.Z + 16384 + byte);
      }
#pragma unroll
      for (int q = 0; q < 2; q++) {
        const int nt = ntp * 2 + q;
        acc[nt] = __builtin_amdgcn_mfma_f32_16x16x32_bf16(ah, bh[q], acc[nt], 0, 0, 0);
        acc[nt] = __builtin_amdgcn_mfma_f32_16x16x32_bf16(al, bh[q], acc[nt], 0, 0, 0);
        acc[nt] = __builtin_amdgcn_mfma_f32_16x16x32_bf16(ah, bl[q], acc[nt], 0, 0, 0);
      }
    }
  }
  __syncthreads();
  {
    unsigned* ZH = sm.Z;
    unsigned* ZL = sm.Z + 4096;
    const int j0 = w * 16 + lg * 4;
    const float4 b4 = *(const float4*)(bemb + j0);
#pragma unroll
    for (int nt = 0; nt < 4; nt++) {
      const int r = l15 + nt * 16;
      const float v0 = acc[nt][0] + b4.x, v1 = acc[nt][1] + b4.y;
      const float v2 = acc[nt][2] + b4.z, v3 = acc[nt][3] + b4.w;
      unsigned h0, l0, h1, l1;
      split_pk(v0, v1, h0, l0); split_pk(v2, v3, h1, l1);
      const int wd = (r << 6) + ((j0 >> 1) ^ ((r & 7) << 2));
      *(uint2*)&ZH[wd] = make_uint2(h0, h1);
      *(uint2*)&ZL[wd] = make_uint2(l0, l1);
    }
  }
  __syncthreads();
}

__device__ __forceinline__ void mlp1(S1& sm, int tid,
    const unsigned short* __restrict__ W1h, const unsigned short* __restrict__ W1l,
    const float* __restrict__ b1, const float* __restrict__ aw, const float* __restrict__ ab,
    const unsigned short* __restrict__ W2h, const unsigned short* __restrict__ W2l,
    const float* __restrict__ b2, const int fout) {
  const int lane = tid & 63, w = tid >> 6, lg = lane >> 4, l15 = lane & 15;
  const int wb = w * 32;

  f32x4 acc[2][4];
#pragma unroll
  for (int mt = 0; mt < 2; mt++)
#pragma unroll
    for (int nt = 0; nt < 4; nt++) acc[mt][nt] = (f32x4){0.f, 0.f, 0.f, 0.f};

#pragma unroll 1
  for (int ks = 0; ks < 4; ks++) {
    const int koff = ks * 32 + lg * 8;
    bf16x8 ah[2], al[2];
#pragma unroll
    for (int mt = 0; mt < 2; mt++) {
      const int c = wb + mt * 16 + l15;
      ah[mt] = *(const bf16x8*)(W1h + c * DD + koff);
      al[mt] = *(const bf16x8*)(W1l + c * DD + koff);
    }
#pragma unroll
    for (int ntp = 0; ntp < 2; ntp++) {
      bf16x8 bh[2], bl[2];
#pragma unroll
      for (int q = 0; q < 2; q++) {
        const int r = l15 + (ntp * 2 + q) * 16;
        const int byte = (r << 8) + ((koff << 1) ^ ((r & 7) << 4));
        bh[q] = *(const bf16x8*)((const char*)sm.Z + byte);
        bl[q] = *(const bf16x8*)((const char*)sm.Z + 16384 + byte);
      }
#pragma unroll
      for (int mt = 0; mt < 2; mt++)
#pragma unroll
        for (int q = 0; q < 2; q++) {
          const int nt = ntp * 2 + q;
          acc[mt][nt] = __builtin_amdgcn_mfma_f32_16x16x32_bf16(ah[mt], bh[q], acc[mt][nt], 0, 0, 0);
          acc[mt][nt] = __builtin_amdgcn_mfma_f32_16x16x32_bf16(al[mt], bh[q], acc[mt][nt], 0, 0, 0);
          acc[mt][nt] = __builtin_amdgcn_mfma_f32_16x16x32_bf16(ah[mt], bl[q], acc[mt][nt], 0, 0, 0);
        }
    }
  }
#pragma unroll
  for (int mt = 0; mt < 2; mt++) {
    const float4 b4 = *(const float4*)(b1 + wb + mt * 16 + lg * 4);
#pragma unroll
    for (int nt = 0; nt < 4; nt++) {
      acc[mt][nt][0] += b4.x; acc[mt][nt][1] += b4.y;
      acc[mt][nt][2] += b4.z; acc[mt][nt][3] += b4.w;
    }
  }
#pragma unroll
  for (int nt = 0; nt < 4; nt++) {
    float s = 0.f;
#pragma unroll
    for (int mt = 0; mt < 2; mt++)
      s += acc[mt][nt][0] + acc[mt][nt][1] + acc[mt][nt][2] + acc[mt][nt][3];
    s += __shfl_xor(s, 16, 64); s += __shfl_xor(s, 32, 64);
    if (lg == 0) sm.red[l15 + nt * 16][w] = s;
  }
  __syncthreads();
  if (tid < 64) {
    float t = 0.f;
#pragma unroll
    for (int q = 0; q < 8; q++) t += sm.red[tid][q];
    sm.stats[tid][0] = t * (1.f / H2);
  }
  __syncthreads();
#pragma unroll
  for (int nt = 0; nt < 4; nt++) {
    const float mu = sm.stats[l15 + nt * 16][0];
    float s = 0.f;
#pragma unroll
    for (int mt = 0; mt < 2; mt++)
#pragma unroll
      for (int q = 0; q < 4; q++) { const float d = acc[mt][nt][q] - mu; s += d * d; }
    s += __shfl_xor(s, 16, 64); s += __shfl_xor(s, 32, 64);
    if (lg == 0) sm.red[l15 + nt * 16][w] = s;
  }
  __syncthreads();
  if (tid < 64) {
    float t = 0.f;
#pragma unroll
    for (int q = 0; q < 8; q++) t += sm.red[tid][q];
    sm.stats[tid][1] = 1.0f / sqrtf(t * (1.f / H2) + 1e-5f);
  }
  __syncthreads();

  {
    unsigned* thi = sm.Z;
#pragma unroll
    for (int nt = 0; nt < 4; nt++) {
      const int r = l15 + nt * 16;
      const float mu = sm.stats[r][0], rs = sm.stats[r][1];
#pragma unroll
      for (int mt = 0; mt < 2; mt++) {
        const float4 aw4 = *(const float4*)(aw + wb + mt * 16 + lg * 4);
        const float4 ab4 = *(const float4*)(ab + wb + mt * 16 + lg * 4);
        const float t0 = fmaxf(aw4.x * (acc[mt][nt][0] - mu) * rs + ab4.x, 0.f);
        const float t1 = fmaxf(aw4.y * (acc[mt][nt][1] - mu) * rs + ab4.y, 0.f);
        const float t2 = fmaxf(aw4.z * (acc[mt][nt][2] - mu) * rs + ab4.z, 0.f);
        const float t3 = fmaxf(aw4.w * (acc[mt][nt][3] - mu) * rs + ab4.w, 0.f);
        unsigned h0, l0, h1, l1;
        split_pk(t0, t1, h0, l0); split_pk(t2, t3, h1, l1);
        const int c2w = w * 16 + mt * 8 + lg * 2;
        const int wd = (r << 7) + (c2w ^ ((r & 7) << 2));
        *(uint2*)&thi[wd] = make_uint2(h0, h1);
        *(uint2*)&sm.Tl[wd] = make_uint2(l0, l1);
      }
    }
  }
  __syncthreads();

  f32x4 acc2[4];
#pragma unroll
  for (int nt = 0; nt < 4; nt++) acc2[nt] = (f32x4){0.f, 0.f, 0.f, 0.f};

  {
    const unsigned* thi = sm.Z;
#pragma unroll 1
    for (int kk = 0; kk < 8; kk++) {
      const int cs = kk * 16 + lg * 4;
      const int cglob = kk * 32 + lg * 8;
      const int j = w * 16 + l15;
      const bf16x8 wh = *(const bf16x8*)(W2h + j * H2 + cglob);
      const bf16x8 wl = *(const bf16x8*)(W2l + j * H2 + cglob);
#pragma unroll
      for (int ntp = 0; ntp < 2; ntp++) {
        bf16x8 th[2], tl[2];
#pragma unroll
        for (int q = 0; q < 2; q++) {
          const int r = l15 + (ntp * 2 + q) * 16;
          const int wd = (r << 7) + (cs ^ ((r & 7) << 2));
          th[q] = *(const bf16x8*)&thi[wd];
          tl[q] = *(const bf16x8*)&sm.Tl[wd];
        }
#pragma unroll
        for (int q = 0; q < 2; q++) {
          const int nt = ntp * 2 + q;
          acc2[nt] = __builtin_amdgcn_mfma_f32_16x16x32_bf16(wh, th[q], acc2[nt], 0, 0, 0);
          acc2[nt] = __builtin_amdgcn_mfma_f32_16x16x32_bf16(wl, th[q], acc2[nt], 0, 0, 0);
          acc2[nt] = __builtin_amdgcn_mfma_f32_16x16x32_bf16(wh, tl[q], acc2[nt], 0, 0, 0);
        }
      }
    }
  }

  __syncthreads();
  unsigned* ZH = sm.Z;
  unsigned* ZL = sm.Z + 4096;
  const int j0 = w * 16 + lg * 4;
  const float4 b4 = *(const float4*)(b2 + j0);
  if (!fout) {
#pragma unroll
    for (int nt = 0; nt < 4; nt++) {
      const int r = l15 + nt * 16;
      const float v0 = acc2[nt][0] + b4.x, v1 = acc2[nt][1] + b4.y;
      const float v2 = acc2[nt][2] + b4.z, v3 = acc2[nt][3] + b4.w;
      unsigned h0, l0, h1, l1;
      split_pk(v0, v1, h0, l0); split_pk(v2, v3, h1, l1);
      const int wd = (r << 6) + ((j0 >> 1) ^ ((r & 7) << 2));
      *(uint2*)&ZH[wd] = make_uint2(h0, h1);
      *(uint2*)&ZL[wd] = make_uint2(l0, l1);
    }
  } else {
    float* M = (float*)sm.Z;
    const int k0 = j0 >> 2;
#pragma unroll
    for (int nt = 0; nt < 4; nt++) {
      const int r = l15 + nt * 16;
      *(float4*)&M[(r << 7) + ((k0 ^ (r & 7)) << 2)] =
          make_float4(acc2[nt][0] + b4.x, acc2[nt][1] + b4.y,
                      acc2[nt][2] + b4.z, acc2[nt][3] + b4.w);
    }
  }
  __syncthreads();
}

__global__ __launch_bounds__(512, 4) void k1_gnn_score(
    const float* __restrict__ x, const int* __restrict__ EI,
    const unsigned short* __restrict__ eh, const unsigned short* __restrict__ el,
    const float* __restrict__ bemb,
    const unsigned short* __restrict__ g1h, const unsigned short* __restrict__ g1l,
    const float* __restrict__ gb1, const float* __restrict__ gaw, const float* __restrict__ gab,
    const unsigned short* __restrict__ g2h, const unsigned short* __restrict__ g2l,
    const float* __restrict__ gb2,
    const unsigned short* __restrict__ m1h, const unsigned short* __restrict__ m1l,
    const float* __restrict__ mb1, const float* __restrict__ maw, const float* __restrict__ mab,
    const unsigned short* __restrict__ m2h, const unsigned short* __restrict__ m2l,
    const float* __restrict__ mb2,
    unsigned* __restrict__ repb, float* __restrict__ esc, float* __restrict__ gmm) {
  __shared__ S1 sm;
  const int g = blockIdx.x, tid = threadIdx.x;
  unsigned* ZH = sm.Z;
  unsigned* ZL = sm.Z + 4096;

  for (int idx = tid; idx < 64 * 64; idx += 512) {
    const int r = idx >> 6, f2 = idx & 63;
    float x0 = 0.f, x1 = 0.f;
    if (r < NPG) {
      const float2 v = *(const float2*)&x[(size_t)(g * NPG + r) * DD + 2 * f2];
      x0 = v.x; x1 = v.y;
    }
    unsigned ph, pl;
    split_pk(x0, x1, ph, pl);
    const int wd = zb_word(r, f2);
    ZH[wd] = ph; ZL[wd] = pl;
  }
  build_csr<512>(sm, tid, EI, g);

  embed_mfma(sm, tid, eh, el, bemb);

  for (int l = 0; l < 2; l++) {
    gather_s(sm, tid);
    mlp1(sm, tid, g1h + l * H2 * DD, g1l + l * H2 * DD, gb1 + l * H2, gaw + l * H2, gab + l * H2,
         g2h + l * H2 * DD, g2l + l * H2 * DD, gb2 + l * DD, 0);
  }
  for (int idx = tid; idx < NPG * 64; idx += 512) {
    const int r = idx >> 6, f2 = idx & 63;
    repb[(size_t)(g * NPG + r) * 64 + f2] = ZH[zb_word(r, f2)];
  }
  mlp1(sm, tid, m1h, m1l, mb1, maw, mab, m2h, m2l, mb2, 1);

  const float* M = (const float*)sm.Z;
  float mn = 3.402823466e38f, mx = -3.402823466e38f;
  for (int e = tid; e < EPG; e += 512) {
    const int r = sm.erow[e], cn = sm.ecol[e];
    const int sr = (r & 7), sc = (cn & 7);
    float acc = 0.0f;
    for (int k0 = 0; k0 < 32; k0++) {
      const float4 a = *(const float4*)&M[(r << 7) + ((k0 ^ sr) << 2)];
      const float4 b = *(const float4*)&M[(cn << 7) + ((k0 ^ sc) << 2)];
      acc += a.x * b.x; acc += a.y * b.y; acc += a.z * b.z; acc += a.w * b.w;
    }
    const float scv = acc * (1.0f / DD);
    esc[g * EPG + e] = scv;
    mn = fminf(mn, scv); mx = fmaxf(mx, scv);
  }
#pragma unroll
  for (int m = 1; m < 64; m <<= 1) {
    mn = fminf(mn, __shfl_xor(mn, m, 64));
    mx = fmaxf(mx, __shfl_xor(mx, m, 64));
  }
  const int lane = tid & 63, wid = tid >> 6;
  if (lane == 0) { sm.red[0][wid] = mn; sm.red[1][wid] = mx; }
  __syncthreads();
  if (tid == 0) {
    float a = sm.red[0][0], b = sm.red[1][0];
#pragma unroll
    for (int q = 1; q < 8; q++) { a = fminf(a, sm.red[0][q]); b = fmaxf(b, sm.red[1][q]); }
    gmm[g] = a; gmm[NG + g] = b;
  }
}

// ---------- kernel 2: global min/max ----------

__global__ __launch_bounds__(256) void k2_minmax(const float* __restrict__ gmm,
                                                 float* __restrict__ smm) {
  __shared__ float ra[4], rb[4];
  const int tid = threadIdx.x;
  float mn = 3.402823466e38f, mx = -3.402823466e38f;
  for (int i = tid; i < NG; i += 256) {
    mn = fminf(mn, gmm[i]);
    mx = fmaxf(mx, gmm[NG + i]);
  }
#pragma unroll
  for (int m = 1; m < 64; m <<= 1) {
    mn = fminf(mn, __shfl_xor(mn, m, 64));
    mx = fmaxf(mx, __shfl_xor(mx, m, 64));
  }
  const int lane = tid & 63, wid = tid >> 6;
  if (lane == 0) { ra[wid] = mn; rb[wid] = mx; }
  __syncthreads();
  if (tid == 0) {
    smm[0] = fminf(fminf(ra[0], ra[1]), fminf(ra[2], ra[3]));
    smm[1] = fmaxf(fmaxf(rb[0], rb[1]), fmaxf(rb[2], rb[3]));
  }
}

// ---------- k3 (512 threads; fe_mlp mirrors k1's proven spill-free mlp1) ----------

__device__ __forceinline__ void gather3(Smem3& sm, int tid) {
  const int f2 = tid & 63, rg = tid >> 6;
  const int r0 = (rg < 2) ? rg * 7 : 14 + (rg - 2) * 6;
  const int rn = (rg < 2) ? 7 : 6;
  float a0[7], a1[7];
#pragma unroll
  for (int i = 0; i < 7; i++) {
    if (i < rn) {
      const int r = r0 + i;
      const unsigned u = sm.Zb[zb_word(r, f2)];
      float x0 = ubf_lo(u), x1 = ubf_hi(u);
      const int p0 = sm.offs[r], p1 = sm.offs[r + 1];
      for (int p = p0; p < p1; p++) {
        const int ad = sm.adj[p];
        const int cn = ad >> 10;
        const float wg = sm.cw[ad & 1023];
        const unsigned v = sm.Zb[zb_word(cn, f2)];
        x0 = fmaf(wg, ubf_lo(v), x0);
        x1 = fmaf(wg, ubf_hi(v), x1);
      }
      a0[i] = x0; a1[i] = x1;
    }
  }
  __syncthreads();
#pragma unroll
  for (int i = 0; i < 7; i++) {
    if (i < rn) sm.Zb[zb_word(r0 + i, f2)] = pk2(a0[i], a1[i]);
  }
  __syncthreads();
}

__device__ __forceinline__ void fe_mlp(Smem3& sm, int tid,
    const unsigned short* __restrict__ W1t, const unsigned short* __restrict__ W2t,
    const float* __restrict__ b1, const float* __restrict__ aw, const float* __restrict__ ab,
    const float* __restrict__ b2, float* __restrict__ outp) {
  const int lane = tid & 63, w = tid >> 6, lg = lane >> 4, l15 = lane & 15;
  const int wb = w * 32;

  // ---- GEMM1: M=256 c (8 waves x 32), N=64 r, K=128 ----
  f32x4 acc[2][4];
#pragma unroll
  for (int mt = 0; mt < 2; mt++)
#pragma unroll
    for (int nt = 0; nt < 4; nt++) acc[mt][nt] = (f32x4){0.f, 0.f, 0.f, 0.f};

#pragma unroll 1
  for (int ks = 0; ks < 4; ks++) {
    const int koff = ks * 32 + lg * 8;
    bf16x8 afr[2];
#pragma unroll
    for (int mt = 0; mt < 2; mt++) {
      const int c = wb + mt * 16 + l15;
      afr[mt] = *(const bf16x8*)(W1t + c * DD + koff);
    }
#pragma unroll
    for (int ntp = 0; ntp < 2; ntp++) {
      bf16x8 bfr[2];
#pragma unroll
      for (int q = 0; q < 2; q++) {
        const int r = l15 + (ntp * 2 + q) * 16;
        const int byte = (r << 8) + ((koff << 1) ^ ((r & 7) << 4));
        bfr[q] = *(const bf16x8*)((const char*)sm.Zb + byte);
      }
#pragma unroll
      for (int mt = 0; mt < 2; mt++)
#pragma unroll
        for (int q = 0; q < 2; q++)
          acc[mt][ntp * 2 + q] =
              __builtin_amdgcn_mfma_f32_16x16x32_bf16(afr[mt], bfr[q], acc[mt][ntp * 2 + q], 0, 0, 0);
    }
  }
  // + b1
#pragma unroll
  for (int mt = 0; mt < 2; mt++) {
    const float4 b4 = *(const float4*)(b1 + wb + mt * 16 + lg * 4);
#pragma unroll
    for (int nt = 0; nt < 4; nt++) {
      acc[mt][nt][0] += b4.x; acc[mt][nt][1] += b4.y;
      acc[mt][nt][2] += b4.z; acc[mt][nt][3] += b4.w;
    }
  }
  // ---- norm stats ----
#pragma unroll
  for (int nt = 0; nt < 4; nt++) {
    float s = 0.f;
#pragma unroll
    for (int mt = 0; mt < 2; mt++)
      s += acc[mt][nt][0] + acc[mt][nt][1] + acc[mt][nt][2] + acc[mt][nt][3];
    s += __shfl_xor(s, 16, 64); s += __shfl_xor(s, 32, 64);
    if (lg == 0) sm.red[l15 + nt * 16][w] = s;
  }
  __syncthreads();      // all GEMM1 Zb reads complete past this point
  if (tid < 64) {
    float t = 0.f;
#pragma unroll
    for (int q = 0; q < 8; q++) t += sm.red[tid][q];
    sm.stats[tid][0] = t * (1.f / H2);
  }
  __syncthreads();
#pragma unroll
  for (int nt = 0; nt < 4; nt++) {
    const float mu = sm.stats[l15 + nt * 16][0];
    float s = 0.f;
#pragma unroll
    for (int mt = 0; mt < 2; mt++)
#pragma unroll
      for (int q = 0; q < 4; q++) { const float d = acc[mt][nt][q] - mu; s += d * d; }
    s += __shfl_xor(s, 16, 64); s += __shfl_xor(s, 32, 64);
    if (lg == 0) sm.red[l15 + nt * 16][w] = s;
  }
  __syncthreads();
  if (tid < 64) {
    float t = 0.f;
#pragma unroll
    for (int q = 0; q < 8; q++) t += sm.red[tid][q];
    sm.stats[tid][1] = 1.0f / sqrtf(t * (1.f / H2) + 1e-5f);
  }
  __syncthreads();

  // ---- affine + relu: all waves write full T (acc dies here) ----
  {
#pragma unroll
    for (int nt = 0; nt < 4; nt++) {
      const int r = l15 + nt * 16;
      const float mu = sm.stats[r][0], rs = sm.stats[r][1];
#pragma unroll
      for (int mt = 0; mt < 2; mt++) {
        const float4 aw4 = *(const float4*)(aw + wb + mt * 16 + lg * 4);
        const float4 ab4 = *(const float4*)(ab + wb + mt * 16 + lg * 4);
        const float t0 = fmaxf(aw4.x * (acc[mt][nt][0] - mu) * rs + ab4.x, 0.f);
        const float t1 = fmaxf(aw4.y * (acc[mt][nt][1] - mu) * rs + ab4.y, 0.f);
        const float t2 = fmaxf(aw4.z * (acc[mt][nt][2] - mu) * rs + ab4.z, 0.f);
        const float t3 = fmaxf(aw4.w * (acc[mt][nt][3] - mu) * rs + ab4.w, 0.f);
        const int c2w = w * 16 + mt * 8 + lg * 2;
        const int wd = (r << 7) + (c2w ^ ((r & 7) << 2));
        *(uint2*)&sm.T[wd] = make_uint2(pk2(t0, t1), pk2(t2, t3));
      }
    }
  }
  __syncthreads();

  // ---- GEMM2: M=128 j (8 waves x 16), N=64 r, K=256 flat in 8 steps ----
  f32x4 acc2[4];
#pragma unroll
  for (int nt = 0; nt < 4; nt++) acc2[nt] = (f32x4){0.f, 0.f, 0.f, 0.f};

#pragma unroll 1
  for (int kk = 0; kk < 8; kk++) {
    const int cs = kk * 16 + lg * 4;
    const int cglob = kk * 32 + lg * 8;
    const int j = w * 16 + l15;
    const bf16x8 wh = *(const bf16x8*)(W2t + j * H2 + cglob);
#pragma unroll
    for (int ntp = 0; ntp < 2; ntp++) {
      bf16x8 th[2];
#pragma unroll
      for (int q = 0; q < 2; q++) {
        const int r = l15 + (ntp * 2 + q) * 16;
        const int wd = (r << 7) + (cs ^ ((r & 7) << 2));
        th[q] = *(const bf16x8*)&sm.T[wd];
      }
#pragma unroll
      for (int q = 0; q < 2; q++)
        acc2[ntp * 2 + q] =
            __builtin_amdgcn_mfma_f32_16x16x32_bf16(wh, th[q], acc2[ntp * 2 + q], 0, 0, 0);
    }
  }

  const int j0 = w * 16 + lg * 4;
  const float4 b4 = *(const float4*)(b2 + j0);
  if (outp == nullptr) {
#pragma unroll
    for (int nt = 0; nt < 4; nt++) {
      const int r = l15 + nt * 16;
      if (r < NPG) {
        const float v0 = acc2[nt][0] + b4.x, v1 = acc2[nt][1] + b4.y;
        const float v2 = acc2[nt][2] + b4.z, v3 = acc2[nt][3] + b4.w;
        const int f2 = j0 >> 1;
        const int wd = (r << 6) + (f2 ^ ((r & 7) << 2));
        *(uint2*)&sm.Zb[wd] = make_uint2(pk2(v0, v1), pk2(v2, v3));
      }
    }
    __syncthreads();
  } else {
    float s0 = 0.f, s1 = 0.f, s2 = 0.f, s3 = 0.f;
#pragma unroll
    for (int nt = 0; nt < 4; nt++) {
      const int r = l15 + nt * 16;
      const float m = sm.mask[r];
      s0 = fmaf(m, acc2[nt][0] + b4.x, s0);
      s1 = fmaf(m, acc2[nt][1] + b4.y, s1);
      s2 = fmaf(m, acc2[nt][2] + b4.z, s2);
      s3 = fmaf(m, acc2[nt][3] + b4.w, s3);
    }
#pragma unroll
    for (int msk = 1; msk < 16; msk <<= 1) {
      s0 += __shfl_xor(s0, msk, 64); s1 += __shfl_xor(s1, msk, 64);
      s2 += __shfl_xor(s2, msk, 64); s3 += __shfl_xor(s3, msk, 64);
    }
    if (l15 == 0) {
      const float ic = 1.0f / sm.cnt;
      *(float4*)(outp + j0) = make_float4(s0 * ic, s1 * ic, s2 * ic, s3 * ic);
    }
  }
}

__global__ __launch_bounds__(512, 4) void k3_select_fe(
    const int* __restrict__ EI,
    const unsigned short* __restrict__ W1t, const unsigned short* __restrict__ W2t,
    const float* __restrict__ fb1, const float* __restrict__ faw,
    const float* __restrict__ fab, const float* __restrict__ fb2,
    const unsigned* __restrict__ repb, const float* __restrict__ esc,
    const float* __restrict__ smm, float* __restrict__ out) {
  __shared__ Smem3 sm;
  const int g = blockIdx.x, tid = threadIdx.x;

  build_csr<512>(sm, tid, EI, g);

  const float smin = smm[0], smax = smm[1];
  const float denom = (smax - smin) + 1e-12f;
  for (int e = tid; e < EPG; e += 512) {
    const float sc = esc[g * EPG + e];
    sm.s[e] = sc;
    sm.key[e] = (sc - smin) / denom - (float)g;  // exact reference key arithmetic
  }
  for (int i = tid; i < 64; i += 512) sm.mask[i] = 0.0f;
  for (int idx = tid; idx < 64 * 64; idx += 512) {
    const int r = idx >> 6, f2 = idx & 63;
    unsigned p = 0u;
    if (r < NPG) p = repb[(size_t)(g * NPG + r) * 64 + f2];
    sm.Zb[zb_word(r, f2)] = p;
  }
  __syncthreads();

  // stable-descending rank (identical to rounds 1-10 -> identical selection)
  for (int e = tid; e < EPG; e += 512) {
    const float ki = sm.key[e];
    int cntk = 0;
    for (int j2 = 0; j2 < EPG; j2++) {
      const float kj = sm.key[j2];
      cntk += ((kj > ki) || ((kj == ki) && (j2 < e))) ? 1 : 0;
    }
    const bool kept = cntk < KEEP;
    sm.cw[e] = kept ? sm.s[e] : 0.0f;
    if (kept) {
      sm.mask[sm.erow[e]] = 1.0f;
      sm.mask[sm.ecol[e]] = 1.0f;
    }
  }
  __syncthreads();
  if (tid == 0) {
    float cc = 0.f;
    for (int r = 0; r < NPG; r++) cc += sm.mask[r];
    sm.cnt = fmaxf(cc, 1.0f);
  }
  __syncthreads();

  for (int l = 0; l < 3; l++) {
    gather3(sm, tid);
    fe_mlp(sm, tid, W1t + l * H2 * DD, W2t + l * H2 * DD,
           fb1 + l * H2, faw + l * H2, fab + l * H2, fb2 + l * DD,
           (l == 2) ? (out + (size_t)g * DD) : nullptr);
  }
}

// ---------- launch ----------

extern "C" void kernel_launch(void* const* d_in, const int* in_sizes, int n_in,
                              void* d_out, int out_size, void* d_ws, size_t ws_size,
                              hipStream_t stream) {
  (void)in_sizes; (void)n_in; (void)out_size; (void)ws_size;
  const float* x    = (const float*)d_in[0];
  const int*   EI   = (const int*)d_in[1];
  const float* Wemb = (const float*)d_in[3];
  const float* bemb = (const float*)d_in[4];
  const float* gW1  = (const float*)d_in[5];
  const float* gb1  = (const float*)d_in[6];
  const float* gaw  = (const float*)d_in[7];
  const float* gab  = (const float*)d_in[8];
  const float* gW2  = (const float*)d_in[9];
  const float* gb2  = (const float*)d_in[10];
  const float* mW1  = (const float*)d_in[11];
  const float* mb1  = (const float*)d_in[12];
  const float* maw  = (const float*)d_in[13];
  const float* mab  = (const float*)d_in[14];
  const float* mW2  = (const float*)d_in[15];
  const float* mb2  = (const float*)d_in[16];
  const float* fW1  = (const float*)d_in[17];
  const float* fb1  = (const float*)d_in[18];
  const float* faw  = (const float*)d_in[19];
  const float* fab  = (const float*)d_in[20];
  const float* fW2  = (const float*)d_in[21];
  const float* fb2  = (const float*)d_in[22];

  unsigned short* p = (unsigned short*)d_ws;
  unsigned short* fW1t = p; p += 3 * H2 * DD;
  unsigned short* fW2t = p; p += 3 * H2 * DD;
  unsigned short* eh   = p; p += DD * DD;
  unsigned short* el   = p; p += DD * DD;
  unsigned short* g1h  = p; p += 2 * H2 * DD;
  unsigned short* g1l  = p; p += 2 * H2 * DD;
  unsigned short* g2h  = p; p += 2 * H2 * DD;
  unsigned short* g2l  = p; p += 2 * H2 * DD;
  unsigned short* m1h  = p; p += H2 * DD;
  unsigned short* m1l  = p; p += H2 * DD;
  unsigned short* m2h  = p; p += H2 * DD;
  unsigned short* m2l  = p; p += H2 * DD;
  unsigned* repb = (unsigned*)p;
  float* esc = (float*)(repb + (size_t)NN * 64);
  float* gmm = esc + NE;
  float* smm = gmm + 2 * NG;
  float* out = (float*)d_out;

  k_wconv<<<(3 * H2 * DD + 255) / 256, 256, 0, stream>>>(
      Wemb, gW1, gW2, mW1, mW2, fW1, fW2,
      fW1t, fW2t, eh, el, g1h, g1l, g2h, g2l, m1h, m1l, m2h, m2l);
  k1_gnn_score<<<NG, 512, 0, stream>>>(x, EI, eh, el, bemb,
                                       g1h, g1l, gb1, gaw, gab, g2h, g2l, gb2,
                                       m1h, m1l, mb1, maw, mab, m2h, m2l, mb2,
                                       repb, esc, gmm);
  k2_minmax<<<1, 256, 0, stream>>>(gmm, smm);
  k3_select_fe<<<NG, 512, 0, stream>>>(EI, fW1t, fW2t, fb1, faw, fab, fb2, repb, esc, smm, out);
}

// Round 12
// 451.213 us; speedup vs baseline: 1.5145x; 1.3168x over previous
//
#include <hip/hip_runtime.h>
#include <hip/hip_bf16.h>

#define NG   1000
#define NPG  50
#define EPG  600
#define NE   600000
#define NN   50000
#define DD   128
#define H2   256
#define KEEP 300

typedef __attribute__((ext_vector_type(8))) short bf16x8;
typedef __attribute__((ext_vector_type(4))) float f32x4;

// ---------- bf16 helpers ----------

__device__ __forceinline__ unsigned short bfb(float x) {
  __hip_bfloat16 h = __float2bfloat16(x);
  union { __hip_bfloat16 h; unsigned short u; } cv; cv.h = h; return cv.u;
}
__device__ __forceinline__ float ubfs(unsigned short u) {
  union { unsigned u; float f; } c; c.u = ((unsigned)u) << 16; return c.f;
}
__device__ __forceinline__ unsigned pk2(float a, float b) {
  return (unsigned)bfb(a) | ((unsigned)bfb(b) << 16);
}
__device__ __forceinline__ float ubf_lo(unsigned u) {
  union { unsigned u; float f; } c; c.u = u << 16; return c.f;
}
__device__ __forceinline__ float ubf_hi(unsigned u) {
  union { unsigned u; float f; } c; c.u = u & 0xffff0000u; return c.f;
}
__device__ __forceinline__ void split2(float x, unsigned short& h, unsigned short& l) {
  h = bfb(x);
  l = bfb(x - ubfs(h));
}
__device__ __forceinline__ void split_pk(float a, float b, unsigned& ph, unsigned& pl) {
  unsigned short ha, la, hb, lb;
  split2(a, ha, la); split2(b, hb, lb);
  ph = (unsigned)ha | ((unsigned)hb << 16);
  pl = (unsigned)la | ((unsigned)lb << 16);
}

// swizzled u32 index into a [64][64]-u32 row-major tile
__device__ __forceinline__ int zb_word(int r, int f2) {
  return (r << 6) + (f2 ^ ((r & 7) << 2));
}

// ---------- shared memory structs ----------

struct __align__(16) S1 {                // k1 (split precision, 512 threads)
  unsigned Z[8192];                      // 32 KB: Zh/Zl; doubles as T-hi and f32 M tile
  unsigned Tl[8192];                     // 32 KB: T-lo
  float red[64][8];
  float stats[64][2];
  unsigned short erow[EPG];              // 8B-aligned (offset 68096)
  unsigned short ecol[EPG];
  unsigned short adj[EPG];
  int offs[NPG + 1];
  int deg[NPG];
};                                       // ~70.4 KB -> 2 blocks/CU

struct __align__(16) Smem3 {             // k3 (512 threads)
  unsigned Zb[4096];                     // 16 KB activations
  unsigned T[8192];                      // 32 KB full T
  float red[64][8];
  float stats[64][2];
  float s[EPG];
  float key[EPG] __attribute__((aligned(16)));
  float cw[EPG];
  unsigned short erow[EPG];
  unsigned short ecol[EPG];
  unsigned short adj[EPG];
  int offs[NPG + 1];
  float mask[64];
  float cnt;
};                                       // ~61.7 KB -> 2 blocks/CU

// ---------- k1 CSR build (wave-scan prefix + ushort4 fill) + persist ----------

__device__ __forceinline__ void build_csr_fast(S1& sm, int tid, const int* __restrict__ EI,
                                               int g, unsigned short* __restrict__ gadj,
                                               int* __restrict__ goffs) {
  for (int e = tid; e < EPG; e += 512) {
    int re = EI[g * EPG + e] - g * NPG;
    int ce = EI[NE + g * EPG + e] - g * NPG;
    sm.erow[e] = (unsigned short)re;
    sm.ecol[e] = (unsigned short)ce;
  }
  for (int i = tid; i < NPG; i += 512) sm.deg[i] = 0;
  __syncthreads();
  for (int e = tid; e < EPG; e += 512) atomicAdd(&sm.deg[sm.erow[e]], 1);
  __syncthreads();
  if (tid < 64) {  // wave-parallel inclusive scan (replaces serial tid==0 loop)
    int s = (tid < NPG) ? sm.deg[tid] : 0;
#pragma unroll
    for (int off = 1; off < 64; off <<= 1) {
      const int t = __shfl_up(s, off, 64);
      if (tid >= off) s += t;
    }
    if (tid < NPG) sm.offs[tid + 1] = s;
    if (tid == 0) sm.offs[0] = 0;
  }
  __syncthreads();
  if (tid < NPG) {  // deterministic fill, ushort4-vectorized scan (150 loads vs 600)
    int p = sm.offs[tid];
    for (int eb = 0; eb < EPG; eb += 4) {
      const ushort4 rv = *(const ushort4*)&sm.erow[eb];
      const ushort4 cv = *(const ushort4*)&sm.ecol[eb];
      if ((int)rv.x == tid) sm.adj[p++] = (unsigned short)(((int)cv.x << 10) | (eb + 0));
      if ((int)rv.y == tid) sm.adj[p++] = (unsigned short)(((int)cv.y << 10) | (eb + 1));
      if ((int)rv.z == tid) sm.adj[p++] = (unsigned short)(((int)cv.z << 10) | (eb + 2));
      if ((int)rv.w == tid) sm.adj[p++] = (unsigned short)(((int)cv.w << 10) | (eb + 3));
    }
  }
  __syncthreads();
  for (int e = tid; e < EPG; e += 512) gadj[(size_t)g * EPG + e] = sm.adj[e];
  for (int i = tid; i < NPG + 1; i += 512) goffs[g * (NPG + 1) + i] = sm.offs[i];
}

// ---------- kernel 0: weight conversion ----------

__global__ __launch_bounds__(256) void k_wconv(
    const float* __restrict__ Wemb, const float* __restrict__ gW1, const float* __restrict__ gW2,
    const float* __restrict__ mW1, const float* __restrict__ mW2,
    const float* __restrict__ fW1, const float* __restrict__ fW2,
    unsigned short* __restrict__ fW1t, unsigned short* __restrict__ fW2t,
    unsigned short* __restrict__ eh, unsigned short* __restrict__ el,
    unsigned short* __restrict__ g1h, unsigned short* __restrict__ g1l,
    unsigned short* __restrict__ g2h, unsigned short* __restrict__ g2l,
    unsigned short* __restrict__ m1h, unsigned short* __restrict__ m1l,
    unsigned short* __restrict__ m2h, unsigned short* __restrict__ m2l) {
  const int idx = blockIdx.x * 256 + threadIdx.x;
  if (idx < 3 * H2 * DD) {
    const int l = idx / (H2 * DD), rem = idx % (H2 * DD);
    { const int c = rem >> 7, k = rem & 127; fW1t[idx] = bfb(fW1[l * H2 * DD + k * H2 + c]); }
    { const int j = rem >> 8, c2 = rem & 255; fW2t[idx] = bfb(fW2[l * H2 * DD + c2 * DD + j]); }
  }
  if (idx < DD * DD) {
    const int j = idx >> 7, k = idx & 127;
    split2(Wemb[k * DD + j], eh[idx], el[idx]);
  }
  if (idx < 2 * H2 * DD) {
    const int l = idx >> 15, rem = idx & 32767;
    const int c = rem >> 7, k = rem & 127;
    split2(gW1[l * H2 * DD + k * H2 + c], g1h[idx], g1l[idx]);
  }
  if (idx < 2 * H2 * DD) {
    const int l = idx >> 15, rem = idx & 32767;
    const int j = rem >> 8, c = rem & 255;
    split2(gW2[l * H2 * DD + c * DD + j], g2h[idx], g2l[idx]);
  }
  if (idx < H2 * DD) {
    const int c = idx >> 7, k = idx & 127;
    split2(mW1[k * H2 + c], m1h[idx], m1l[idx]);
  }
  if (idx < H2 * DD) {
    const int j = idx >> 8, c = idx & 255;
    split2(mW2[c * DD + j], m2h[idx], m2l[idx]);
  }
}

// ---------- k1 helpers (unchanged from round 11) ----------

__device__ __forceinline__ void gather_s(S1& sm, int tid) {
  unsigned* ZH = sm.Z;
  unsigned* ZL = sm.Z + 4096;
  const int f2 = tid & 63, rg = tid >> 6;
  const int r0 = (rg < 2) ? rg * 7 : 14 + (rg - 2) * 6;
  const int rn = (rg < 2) ? 7 : 6;
  float a0[7], a1[7];
#pragma unroll
  for (int i = 0; i < 7; i++) {
    if (i < rn) {
      const int r = r0 + i;
      const int wd = zb_word(r, f2);
      const unsigned uh = ZH[wd], ul = ZL[wd];
      float x0 = ubf_lo(uh) + ubf_lo(ul), x1 = ubf_hi(uh) + ubf_hi(ul);
      const int p0 = sm.offs[r], p1 = sm.offs[r + 1];
      for (int p = p0; p < p1; p++) {
        const int cn = sm.adj[p] >> 10;
        const int wc = zb_word(cn, f2);
        const unsigned vh = ZH[wc], vl = ZL[wc];
        x0 += ubf_lo(vh) + ubf_lo(vl);
        x1 += ubf_hi(vh) + ubf_hi(vl);
      }
      a0[i] = x0; a1[i] = x1;
    }
  }
  __syncthreads();
#pragma unroll
  for (int i = 0; i < 7; i++) {
    if (i < rn) {
      const int wd = zb_word(r0 + i, f2);
      unsigned ph, pl;
      split_pk(a0[i], a1[i], ph, pl);
      ZH[wd] = ph; ZL[wd] = pl;
    }
  }
  __syncthreads();
}

__device__ __forceinline__ void embed_mfma(S1& sm, int tid,
    const unsigned short* __restrict__ eh, const unsigned short* __restrict__ el,
    const float* __restrict__ bemb) {
  const int lane = tid & 63, w = tid >> 6, lg = lane >> 4, l15 = lane & 15;
  f32x4 acc[4];
#pragma unroll
  for (int nt = 0; nt < 4; nt++) acc[nt] = (f32x4){0.f, 0.f, 0.f, 0.f};

#pragma unroll 1
  for (int ks = 0; ks < 4; ks++) {
    const int koff = ks * 32 + lg * 8;
    bf16x8 ah, al;
    {
      const int j = w * 16 + l15;
      ah = *(const bf16x8*)(eh + j * DD + koff);
      al = *(const bf16x8*)(el + j * DD + koff);
    }
#pragma unroll
    for (int ntp = 0; ntp < 2; ntp++) {
      bf16x8 bh[2], bl[2];
#pragma unroll
      for (int q = 0; q < 2; q++) {
        const int r = l15 + (ntp * 2 + q) * 16;
        const int byte = (r << 8) + ((koff << 1) ^ ((r & 7) << 4));
        bh[q] = *(const bf16x8*)((const char*)sm.Z + byte);
        bl[q] = *(const bf16x8*)((const char*)sm.Z + 16384 + byte);
      }
#pragma unroll
      for (int q = 0; q < 2; q++) {
        const int nt = ntp * 2 + q;
        acc[nt] = __builtin_amdgcn_mfma_f32_16x16x32_bf16(ah, bh[q], acc[nt], 0, 0, 0);
        acc[nt] = __builtin_amdgcn_mfma_f32_16x16x32_bf16(al, bh[q], acc[nt], 0, 0, 0);
        acc[nt] = __builtin_amdgcn_mfma_f32_16x16x32_bf16(ah, bl[q], acc[nt], 0, 0, 0);
      }
    }
  }
  __syncthreads();
  {
    unsigned* ZH = sm.Z;
    unsigned* ZL = sm.Z + 4096;
    const int j0 = w * 16 + lg * 4;
    const float4 b4 = *(const float4*)(bemb + j0);
#pragma unroll
    for (int nt = 0; nt < 4; nt++) {
      const int r = l15 + nt * 16;
      const float v0 = acc[nt][0] + b4.x, v1 = acc[nt][1] + b4.y;
      const float v2 = acc[nt][2] + b4.z, v3 = acc[nt][3] + b4.w;
      unsigned h0, l0, h1, l1;
      split_pk(v0, v1, h0, l0); split_pk(v2, v3, h1, l1);
      const int wd = (r << 6) + ((j0 >> 1) ^ ((r & 7) << 2));
      *(uint2*)&ZH[wd] = make_uint2(h0, h1);
      *(uint2*)&ZL[wd] = make_uint2(l0, l1);
    }
  }
  __syncthreads();
}

__device__ __forceinline__ void mlp1(S1& sm, int tid,
    const unsigned short* __restrict__ W1h, const unsigned short* __restrict__ W1l,
    const float* __restrict__ b1, const float* __restrict__ aw, const float* __restrict__ ab,
    const unsigned short* __restrict__ W2h, const unsigned short* __restrict__ W2l,
    const float* __restrict__ b2, const int fout) {
  const int lane = tid & 63, w = tid >> 6, lg = lane >> 4, l15 = lane & 15;
  const int wb = w * 32;

  f32x4 acc[2][4];
#pragma unroll
  for (int mt = 0; mt < 2; mt++)
#pragma unroll
    for (int nt = 0; nt < 4; nt++) acc[mt][nt] = (f32x4){0.f, 0.f, 0.f, 0.f};

#pragma unroll 1
  for (int ks = 0; ks < 4; ks++) {
    const int koff = ks * 32 + lg * 8;
    bf16x8 ah[2], al[2];
#pragma unroll
    for (int mt = 0; mt < 2; mt++) {
      const int c = wb + mt * 16 + l15;
      ah[mt] = *(const bf16x8*)(W1h + c * DD + koff);
      al[mt] = *(const bf16x8*)(W1l + c * DD + koff);
    }
#pragma unroll
    for (int ntp = 0; ntp < 2; ntp++) {
      bf16x8 bh[2], bl[2];
#pragma unroll
      for (int q = 0; q < 2; q++) {
        const int r = l15 + (ntp * 2 + q) * 16;
        const int byte = (r << 8) + ((koff << 1) ^ ((r & 7) << 4));
        bh[q] = *(const bf16x8*)((const char*)sm.Z + byte);
        bl[q] = *(const bf16x8*)((const char*)sm.Z + 16384 + byte);
      }
#pragma unroll
      for (int mt = 0; mt < 2; mt++)
#pragma unroll
        for (int q = 0; q < 2; q++) {
          const int nt = ntp * 2 + q;
          acc[mt][nt] = __builtin_amdgcn_mfma_f32_16x16x32_bf16(ah[mt], bh[q], acc[mt][nt], 0, 0, 0);
          acc[mt][nt] = __builtin_amdgcn_mfma_f32_16x16x32_bf16(al[mt], bh[q], acc[mt][nt], 0, 0, 0);
          acc[mt][nt] = __builtin_amdgcn_mfma_f32_16x16x32_bf16(ah[mt], bl[q], acc[mt][nt], 0, 0, 0);
        }
    }
  }
#pragma unroll
  for (int mt = 0; mt < 2; mt++) {
    const float4 b4 = *(const float4*)(b1 + wb + mt * 16 + lg * 4);
#pragma unroll
    for (int nt = 0; nt < 4; nt++) {
      acc[mt][nt][0] += b4.x; acc[mt][nt][1] += b4.y;
      acc[mt][nt][2] += b4.z; acc[mt][nt][3] += b4.w;
    }
  }
#pragma unroll
  for (int nt = 0; nt < 4; nt++) {
    float s = 0.f;
#pragma unroll
    for (int mt = 0; mt < 2; mt++)
      s += acc[mt][nt][0] + acc[mt][nt][1] + acc[mt][nt][2] + acc[mt][nt][3];
    s += __shfl_xor(s, 16, 64); s += __shfl_xor(s, 32, 64);
    if (lg == 0) sm.red[l15 + nt * 16][w] = s;
  }
  __syncthreads();
  if (tid < 64) {
    float t = 0.f;
#pragma unroll
    for (int q = 0; q < 8; q++) t += sm.red[tid][q];
    sm.stats[tid][0] = t * (1.f / H2);
  }
  __syncthreads();
#pragma unroll
  for (int nt = 0; nt < 4; nt++) {
    const float mu = sm.stats[l15 + nt * 16][0];
    float s = 0.f;
#pragma unroll
    for (int mt = 0; mt < 2; mt++)
#pragma unroll
      for (int q = 0; q < 4; q++) { const float d = acc[mt][nt][q] - mu; s += d * d; }
    s += __shfl_xor(s, 16, 64); s += __shfl_xor(s, 32, 64);
    if (lg == 0) sm.red[l15 + nt * 16][w] = s;
  }
  __syncthreads();
  if (tid < 64) {
    float t = 0.f;
#pragma unroll
    for (int q = 0; q < 8; q++) t += sm.red[tid][q];
    sm.stats[tid][1] = 1.0f / sqrtf(t * (1.f / H2) + 1e-5f);
  }
  __syncthreads();

  {
    unsigned* thi = sm.Z;
#pragma unroll
    for (int nt = 0; nt < 4; nt++) {
      const int r = l15 + nt * 16;
      const float mu = sm.stats[r][0], rs = sm.stats[r][1];
#pragma unroll
      for (int mt = 0; mt < 2; mt++) {
        const float4 aw4 = *(const float4*)(aw + wb + mt * 16 + lg * 4);
        const float4 ab4 = *(const float4*)(ab + wb + mt * 16 + lg * 4);
        const float t0 = fmaxf(aw4.x * (acc[mt][nt][0] - mu) * rs + ab4.x, 0.f);
        const float t1 = fmaxf(aw4.y * (acc[mt][nt][1] - mu) * rs + ab4.y, 0.f);
        const float t2 = fmaxf(aw4.z * (acc[mt][nt][2] - mu) * rs + ab4.z, 0.f);
        const float t3 = fmaxf(aw4.w * (acc[mt][nt][3] - mu) * rs + ab4.w, 0.f);
        unsigned h0, l0, h1, l1;
        split_pk(t0, t1, h0, l0); split_pk(t2, t3, h1, l1);
        const int c2w = w * 16 + mt * 8 + lg * 2;
        const int wd = (r << 7) + (c2w ^ ((r & 7) << 2));
        *(uint2*)&thi[wd] = make_uint2(h0, h1);
        *(uint2*)&sm.Tl[wd] = make_uint2(l0, l1);
      }
    }
  }
  __syncthreads();

  f32x4 acc2[4];
#pragma unroll
  for (int nt = 0; nt < 4; nt++) acc2[nt] = (f32x4){0.f, 0.f, 0.f, 0.f};

  {
    const unsigned* thi = sm.Z;
#pragma unroll 1
    for (int kk = 0; kk < 8; kk++) {
      const int cs = kk * 16 + lg * 4;
      const int cglob = kk * 32 + lg * 8;
      const int j = w * 16 + l15;
      const bf16x8 wh = *(const bf16x8*)(W2h + j * H2 + cglob);
      const bf16x8 wl = *(const bf16x8*)(W2l + j * H2 + cglob);
#pragma unroll
      for (int ntp = 0; ntp < 2; ntp++) {
        bf16x8 th[2], tl[2];
#pragma unroll
        for (int q = 0; q < 2; q++) {
          const int r = l15 + (ntp * 2 + q) * 16;
          const int wd = (r << 7) + (cs ^ ((r & 7) << 2));
          th[q] = *(const bf16x8*)&thi[wd];
          tl[q] = *(const bf16x8*)&sm.Tl[wd];
        }
#pragma unroll
        for (int q = 0; q < 2; q++) {
          const int nt = ntp * 2 + q;
          acc2[nt] = __builtin_amdgcn_mfma_f32_16x16x32_bf16(wh, th[q], acc2[nt], 0, 0, 0);
          acc2[nt] = __builtin_amdgcn_mfma_f32_16x16x32_bf16(wl, th[q], acc2[nt], 0, 0, 0);
          acc2[nt] = __builtin_amdgcn_mfma_f32_16x16x32_bf16(wh, tl[q], acc2[nt], 0, 0, 0);
        }
      }
    }
  }

  __syncthreads();
  unsigned* ZH = sm.Z;
  unsigned* ZL = sm.Z + 4096;
  const int j0 = w * 16 + lg * 4;
  const float4 b4 = *(const float4*)(b2 + j0);
  if (!fout) {
#pragma unroll
    for (int nt = 0; nt < 4; nt++) {
      const int r = l15 + nt * 16;
      const float v0 = acc2[nt][0] + b4.x, v1 = acc2[nt][1] + b4.y;
      const float v2 = acc2[nt][2] + b4.z, v3 = acc2[nt][3] + b4.w;
      unsigned h0, l0, h1, l1;
      split_pk(v0, v1, h0, l0); split_pk(v2, v3, h1, l1);
      const int wd = (r << 6) + ((j0 >> 1) ^ ((r & 7) << 2));
      *(uint2*)&ZH[wd] = make_uint2(h0, h1);
      *(uint2*)&ZL[wd] = make_uint2(l0, l1);
    }
  } else {
    float* M = (float*)sm.Z;
    const int k0 = j0 >> 2;
#pragma unroll
    for (int nt = 0; nt < 4; nt++) {
      const int r = l15 + nt * 16;
      *(float4*)&M[(r << 7) + ((k0 ^ (r & 7)) << 2)] =
          make_float4(acc2[nt][0] + b4.x, acc2[nt][1] + b4.y,
                      acc2[nt][2] + b4.z, acc2[nt][3] + b4.w);
    }
  }
  __syncthreads();
}

__global__ __launch_bounds__(512, 4) void k1_gnn_score(
    const float* __restrict__ x, const int* __restrict__ EI,
    const unsigned short* __restrict__ eh, const unsigned short* __restrict__ el,
    const float* __restrict__ bemb,
    const unsigned short* __restrict__ g1h, const unsigned short* __restrict__ g1l,
    const float* __restrict__ gb1, const float* __restrict__ gaw, const float* __restrict__ gab,
    const unsigned short* __restrict__ g2h, const unsigned short* __restrict__ g2l,
    const float* __restrict__ gb2,
    const unsigned short* __restrict__ m1h, const unsigned short* __restrict__ m1l,
    const float* __restrict__ mb1, const float* __restrict__ maw, const float* __restrict__ mab,
    const unsigned short* __restrict__ m2h, const unsigned short* __restrict__ m2l,
    const float* __restrict__ mb2,
    unsigned* __restrict__ repb, float* __restrict__ esc, float* __restrict__ gmm,
    unsigned short* __restrict__ gadj, int* __restrict__ goffs) {
  __shared__ S1 sm;
  const int g = blockIdx.x, tid = threadIdx.x;
  unsigned* ZH = sm.Z;
  unsigned* ZL = sm.Z + 4096;

  for (int idx = tid; idx < 64 * 64; idx += 512) {
    const int r = idx >> 6, f2 = idx & 63;
    float x0 = 0.f, x1 = 0.f;
    if (r < NPG) {
      const float2 v = *(const float2*)&x[(size_t)(g * NPG + r) * DD + 2 * f2];
      x0 = v.x; x1 = v.y;
    }
    unsigned ph, pl;
    split_pk(x0, x1, ph, pl);
    const int wd = zb_word(r, f2);
    ZH[wd] = ph; ZL[wd] = pl;
  }
  build_csr_fast(sm, tid, EI, g, gadj, goffs);

  embed_mfma(sm, tid, eh, el, bemb);

  for (int l = 0; l < 2; l++) {
    gather_s(sm, tid);
    mlp1(sm, tid, g1h + l * H2 * DD, g1l + l * H2 * DD, gb1 + l * H2, gaw + l * H2, gab + l * H2,
         g2h + l * H2 * DD, g2l + l * H2 * DD, gb2 + l * DD, 0);
  }
  for (int idx = tid; idx < NPG * 64; idx += 512) {
    const int r = idx >> 6, f2 = idx & 63;
    repb[(size_t)(g * NPG + r) * 64 + f2] = ZH[zb_word(r, f2)];
  }
  mlp1(sm, tid, m1h, m1l, mb1, maw, mab, m2h, m2l, mb2, 1);

  const float* M = (const float*)sm.Z;
  float mn = 3.402823466e38f, mx = -3.402823466e38f;
  for (int e = tid; e < EPG; e += 512) {
    const int r = sm.erow[e], cn = sm.ecol[e];
    const int sr = (r & 7), sc = (cn & 7);
    float acc = 0.0f;
    for (int k0 = 0; k0 < 32; k0++) {
      const float4 a = *(const float4*)&M[(r << 7) + ((k0 ^ sr) << 2)];
      const float4 b = *(const float4*)&M[(cn << 7) + ((k0 ^ sc) << 2)];
      acc += a.x * b.x; acc += a.y * b.y; acc += a.z * b.z; acc += a.w * b.w;
    }
    const float scv = acc * (1.0f / DD);
    esc[g * EPG + e] = scv;
    mn = fminf(mn, scv); mx = fmaxf(mx, scv);
  }
#pragma unroll
  for (int m = 1; m < 64; m <<= 1) {
    mn = fminf(mn, __shfl_xor(mn, m, 64));
    mx = fmaxf(mx, __shfl_xor(mx, m, 64));
  }
  const int lane = tid & 63, wid = tid >> 6;
  if (lane == 0) { sm.red[0][wid] = mn; sm.red[1][wid] = mx; }
  __syncthreads();
  if (tid == 0) {
    float a = sm.red[0][0], b = sm.red[1][0];
#pragma unroll
    for (int q = 1; q < 8; q++) { a = fminf(a, sm.red[0][q]); b = fmaxf(b, sm.red[1][q]); }
    gmm[g] = a; gmm[NG + g] = b;
  }
}

// ---------- kernel 2: global min/max ----------

__global__ __launch_bounds__(256) void k2_minmax(const float* __restrict__ gmm,
                                                 float* __restrict__ smm) {
  __shared__ float ra[4], rb[4];
  const int tid = threadIdx.x;
  float mn = 3.402823466e38f, mx = -3.402823466e38f;
  for (int i = tid; i < NG; i += 256) {
    mn = fminf(mn, gmm[i]);
    mx = fmaxf(mx, gmm[NG + i]);
  }
#pragma unroll
  for (int m = 1; m < 64; m <<= 1) {
    mn = fminf(mn, __shfl_xor(mn, m, 64));
    mx = fmaxf(mx, __shfl_xor(mx, m, 64));
  }
  const int lane = tid & 63, wid = tid >> 6;
  if (lane == 0) { ra[wid] = mn; rb[wid] = mx; }
  __syncthreads();
  if (tid == 0) {
    smm[0] = fminf(fminf(ra[0], ra[1]), fminf(ra[2], ra[3]));
    smm[1] = fmaxf(fmaxf(rb[0], rb[1]), fmaxf(rb[2], rb[3]));
  }
}

// ---------- k3 (512 threads; CSR loaded from k1; vectorized rank) ----------

__device__ __forceinline__ void gather3(Smem3& sm, int tid) {
  const int f2 = tid & 63, rg = tid >> 6;
  const int r0 = (rg < 2) ? rg * 7 : 14 + (rg - 2) * 6;
  const int rn = (rg < 2) ? 7 : 6;
  float a0[7], a1[7];
#pragma unroll
  for (int i = 0; i < 7; i++) {
    if (i < rn) {
      const int r = r0 + i;
      const unsigned u = sm.Zb[zb_word(r, f2)];
      float x0 = ubf_lo(u), x1 = ubf_hi(u);
      const int p0 = sm.offs[r], p1 = sm.offs[r + 1];
      for (int p = p0; p < p1; p++) {
        const int ad = sm.adj[p];
        const int cn = ad >> 10;
        const float wg = sm.cw[ad & 1023];
        const unsigned v = sm.Zb[zb_word(cn, f2)];
        x0 = fmaf(wg, ubf_lo(v), x0);
        x1 = fmaf(wg, ubf_hi(v), x1);
      }
      a0[i] = x0; a1[i] = x1;
    }
  }
  __syncthreads();
#pragma unroll
  for (int i = 0; i < 7; i++) {
    if (i < rn) sm.Zb[zb_word(r0 + i, f2)] = pk2(a0[i], a1[i]);
  }
  __syncthreads();
}

__device__ __forceinline__ void fe_mlp(Smem3& sm, int tid,
    const unsigned short* __restrict__ W1t, const unsigned short* __restrict__ W2t,
    const float* __restrict__ b1, const float* __restrict__ aw, const float* __restrict__ ab,
    const float* __restrict__ b2, float* __restrict__ outp) {
  const int lane = tid & 63, w = tid >> 6, lg = lane >> 4, l15 = lane & 15;
  const int wb = w * 32;

  f32x4 acc[2][4];
#pragma unroll
  for (int mt = 0; mt < 2; mt++)
#pragma unroll
    for (int nt = 0; nt < 4; nt++) acc[mt][nt] = (f32x4){0.f, 0.f, 0.f, 0.f};

#pragma unroll 1
  for (int ks = 0; ks < 4; ks++) {
    const int koff = ks * 32 + lg * 8;
    bf16x8 afr[2];
#pragma unroll
    for (int mt = 0; mt < 2; mt++) {
      const int c = wb + mt * 16 + l15;
      afr[mt] = *(const bf16x8*)(W1t + c * DD + koff);
    }
#pragma unroll
    for (int ntp = 0; ntp < 2; ntp++) {
      bf16x8 bfr[2];
#pragma unroll
      for (int q = 0; q < 2; q++) {
        const int r = l15 + (ntp * 2 + q) * 16;
        const int byte = (r << 8) + ((koff << 1) ^ ((r & 7) << 4));
        bfr[q] = *(const bf16x8*)((const char*)sm.Zb + byte);
      }
#pragma unroll
      for (int mt = 0; mt < 2; mt++)
#pragma unroll
        for (int q = 0; q < 2; q++)
          acc[mt][ntp * 2 + q] =
              __builtin_amdgcn_mfma_f32_16x16x32_bf16(afr[mt], bfr[q], acc[mt][ntp * 2 + q], 0, 0, 0);
    }
  }
#pragma unroll
  for (int mt = 0; mt < 2; mt++) {
    const float4 b4 = *(const float4*)(b1 + wb + mt * 16 + lg * 4);
#pragma unroll
    for (int nt = 0; nt < 4; nt++) {
      acc[mt][nt][0] += b4.x; acc[mt][nt][1] += b4.y;
      acc[mt][nt][2] += b4.z; acc[mt][nt][3] += b4.w;
    }
  }
#pragma unroll
  for (int nt = 0; nt < 4; nt++) {
    float s = 0.f;
#pragma unroll
    for (int mt = 0; mt < 2; mt++)
      s += acc[mt][nt][0] + acc[mt][nt][1] + acc[mt][nt][2] + acc[mt][nt][3];
    s += __shfl_xor(s, 16, 64); s += __shfl_xor(s, 32, 64);
    if (lg == 0) sm.red[l15 + nt * 16][w] = s;
  }
  __syncthreads();
  if (tid < 64) {
    float t = 0.f;
#pragma unroll
    for (int q = 0; q < 8; q++) t += sm.red[tid][q];
    sm.stats[tid][0] = t * (1.f / H2);
  }
  __syncthreads();
#pragma unroll
  for (int nt = 0; nt < 4; nt++) {
    const float mu = sm.stats[l15 + nt * 16][0];
    float s = 0.f;
#pragma unroll
    for (int mt = 0; mt < 2; mt++)
#pragma unroll
      for (int q = 0; q < 4; q++) { const float d = acc[mt][nt][q] - mu; s += d * d; }
    s += __shfl_xor(s, 16, 64); s += __shfl_xor(s, 32, 64);
    if (lg == 0) sm.red[l15 + nt * 16][w] = s;
  }
  __syncthreads();
  if (tid < 64) {
    float t = 0.f;
#pragma unroll
    for (int q = 0; q < 8; q++) t += sm.red[tid][q];
    sm.stats[tid][1] = 1.0f / sqrtf(t * (1.f / H2) + 1e-5f);
  }
  __syncthreads();

  {
#pragma unroll
    for (int nt = 0; nt < 4; nt++) {
      const int r = l15 + nt * 16;
      const float mu = sm.stats[r][0], rs = sm.stats[r][1];
#pragma unroll
      for (int mt = 0; mt < 2; mt++) {
        const float4 aw4 = *(const float4*)(aw + wb + mt * 16 + lg * 4);
        const float4 ab4 = *(const float4*)(ab + wb + mt * 16 + lg * 4);
        const float t0 = fmaxf(aw4.x * (acc[mt][nt][0] - mu) * rs + ab4.x, 0.f);
        const float t1 = fmaxf(aw4.y * (acc[mt][nt][1] - mu) * rs + ab4.y, 0.f);
        const float t2 = fmaxf(aw4.z * (acc[mt][nt][2] - mu) * rs + ab4.z, 0.f);
        const float t3 = fmaxf(aw4.w * (acc[mt][nt][3] - mu) * rs + ab4.w, 0.f);
        const int c2w = w * 16 + mt * 8 + lg * 2;
        const int wd = (r << 7) + (c2w ^ ((r & 7) << 2));
        *(uint2*)&sm.T[wd] = make_uint2(pk2(t0, t1), pk2(t2, t3));
      }
    }
  }
  __syncthreads();

  f32x4 acc2[4];
#pragma unroll
  for (int nt = 0; nt < 4; nt++) acc2[nt] = (f32x4){0.f, 0.f, 0.f, 0.f};

#pragma unroll 1
  for (int kk = 0; kk < 8; kk++) {
    const int cs = kk * 16 + lg * 4;
    const int cglob = kk * 32 + lg * 8;
    const int j = w * 16 + l15;
    const bf16x8 wh = *(const bf16x8*)(W2t + j * H2 + cglob);
#pragma unroll
    for (int ntp = 0; ntp < 2; ntp++) {
      bf16x8 th[2];
#pragma unroll
      for (int q = 0; q < 2; q++) {
        const int r = l15 + (ntp * 2 + q) * 16;
        const int wd = (r << 7) + (cs ^ ((r & 7) << 2));
        th[q] = *(const bf16x8*)&sm.T[wd];
      }
#pragma unroll
      for (int q = 0; q < 2; q++)
        acc2[ntp * 2 + q] =
            __builtin_amdgcn_mfma_f32_16x16x32_bf16(wh, th[q], acc2[ntp * 2 + q], 0, 0, 0);
    }
  }

  const int j0 = w * 16 + lg * 4;
  const float4 b4 = *(const float4*)(b2 + j0);
  if (outp == nullptr) {
#pragma unroll
    for (int nt = 0; nt < 4; nt++) {
      const int r = l15 + nt * 16;
      if (r < NPG) {
        const float v0 = acc2[nt][0] + b4.x, v1 = acc2[nt][1] + b4.y;
        const float v2 = acc2[nt][2] + b4.z, v3 = acc2[nt][3] + b4.w;
        const int f2 = j0 >> 1;
        const int wd = (r << 6) + (f2 ^ ((r & 7) << 2));
        *(uint2*)&sm.Zb[wd] = make_uint2(pk2(v0, v1), pk2(v2, v3));
      }
    }
    __syncthreads();
  } else {
    float s0 = 0.f, s1 = 0.f, s2 = 0.f, s3 = 0.f;
#pragma unroll
    for (int nt = 0; nt < 4; nt++) {
      const int r = l15 + nt * 16;
      const float m = sm.mask[r];
      s0 = fmaf(m, acc2[nt][0] + b4.x, s0);
      s1 = fmaf(m, acc2[nt][1] + b4.y, s1);
      s2 = fmaf(m, acc2[nt][2] + b4.z, s2);
      s3 = fmaf(m, acc2[nt][3] + b4.w, s3);
    }
#pragma unroll
    for (int msk = 1; msk < 16; msk <<= 1) {
      s0 += __shfl_xor(s0, msk, 64); s1 += __shfl_xor(s1, msk, 64);
      s2 += __shfl_xor(s2, msk, 64); s3 += __shfl_xor(s3, msk, 64);
    }
    if (l15 == 0) {
      const float ic = 1.0f / sm.cnt;
      *(float4*)(outp + j0) = make_float4(s0 * ic, s1 * ic, s2 * ic, s3 * ic);
    }
  }
}

__global__ __launch_bounds__(512, 4) void k3_select_fe(
    const int* __restrict__ EI,
    const unsigned short* __restrict__ W1t, const unsigned short* __restrict__ W2t,
    const float* __restrict__ fb1, const float* __restrict__ faw,
    const float* __restrict__ fab, const float* __restrict__ fb2,
    const unsigned* __restrict__ repb, const float* __restrict__ esc,
    const float* __restrict__ smm, float* __restrict__ out,
    const unsigned short* __restrict__ gadj, const int* __restrict__ goffs) {
  __shared__ Smem3 sm;
  const int g = blockIdx.x, tid = threadIdx.x;

  // stage CSR (persisted by k1) + erow/ecol + keys + Zb
  for (int e = tid; e < EPG; e += 512) {
    sm.adj[e] = gadj[(size_t)g * EPG + e];
    sm.erow[e] = (unsigned short)(EI[g * EPG + e] - g * NPG);
    sm.ecol[e] = (unsigned short)(EI[NE + g * EPG + e] - g * NPG);
  }
  for (int i = tid; i < NPG + 1; i += 512) sm.offs[i] = goffs[g * (NPG + 1) + i];

  const float smin = smm[0], smax = smm[1];
  const float denom = (smax - smin) + 1e-12f;
  for (int e = tid; e < EPG; e += 512) {
    const float sc = esc[g * EPG + e];
    sm.s[e] = sc;
    sm.key[e] = (sc - smin) / denom - (float)g;  // exact reference key arithmetic
  }
  for (int i = tid; i < 64; i += 512) sm.mask[i] = 0.0f;
  for (int idx = tid; idx < 64 * 64; idx += 512) {
    const int r = idx >> 6, f2 = idx & 63;
    unsigned p = 0u;
    if (r < NPG) p = repb[(size_t)(g * NPG + r) * 64 + f2];
    sm.Zb[zb_word(r, f2)] = p;
  }
  __syncthreads();

  // stable-descending rank, float4-vectorized (identical predicates -> identical selection)
  {
    const int e0 = tid, e1 = tid + 512;
    const float k0 = (e0 < EPG) ? sm.key[e0] : 0.f;
    const float k1v = (e1 < EPG) ? sm.key[e1] : 0.f;
    int c0 = 0, c1 = 0;
    for (int j = 0; j < EPG; j += 4) {
      const float4 kv = *(const float4*)&sm.key[j];
      c0 += ((kv.x > k0) || ((kv.x == k0) && (j + 0 < e0))) ? 1 : 0;
      c0 += ((kv.y > k0) || ((kv.y == k0) && (j + 1 < e0))) ? 1 : 0;
      c0 += ((kv.z > k0) || ((kv.z == k0) && (j + 2 < e0))) ? 1 : 0;
      c0 += ((kv.w > k0) || ((kv.w == k0) && (j + 3 < e0))) ? 1 : 0;
      c1 += ((kv.x > k1v) || ((kv.x == k1v) && (j + 0 < e1))) ? 1 : 0;
      c1 += ((kv.y > k1v) || ((kv.y == k1v) && (j + 1 < e1))) ? 1 : 0;
      c1 += ((kv.z > k1v) || ((kv.z == k1v) && (j + 2 < e1))) ? 1 : 0;
      c1 += ((kv.w > k1v) || ((kv.w == k1v) && (j + 3 < e1))) ? 1 : 0;
    }
    if (e0 < EPG) {
      const bool kept = c0 < KEEP;
      sm.cw[e0] = kept ? sm.s[e0] : 0.0f;
      if (kept) { sm.mask[sm.erow[e0]] = 1.0f; sm.mask[sm.ecol[e0]] = 1.0f; }
    }
    if (e1 < EPG) {
      const bool kept = c1 < KEEP;
      sm.cw[e1] = kept ? sm.s[e1] : 0.0f;
      if (kept) { sm.mask[sm.erow[e1]] = 1.0f; sm.mask[sm.ecol[e1]] = 1.0f; }
    }
  }
  __syncthreads();
  if (tid < 64) {  // wave-parallel mask count (integer-exact)
    float c = (tid < NPG) ? sm.mask[tid] : 0.f;
#pragma unroll
    for (int m = 1; m < 64; m <<= 1) c += __shfl_xor(c, m, 64);
    if (tid == 0) sm.cnt = fmaxf(c, 1.0f);
  }
  __syncthreads();

  for (int l = 0; l < 3; l++) {
    gather3(sm, tid);
    fe_mlp(sm, tid, W1t + l * H2 * DD, W2t + l * H2 * DD,
           fb1 + l * H2, faw + l * H2, fab + l * H2, fb2 + l * DD,
           (l == 2) ? (out + (size_t)g * DD) : nullptr);
  }
}

// ---------- launch ----------

extern "C" void kernel_launch(void* const* d_in, const int* in_sizes, int n_in,
                              void* d_out, int out_size, void* d_ws, size_t ws_size,
                              hipStream_t stream) {
  (void)in_sizes; (void)n_in; (void)out_size; (void)ws_size;
  const float* x    = (const float*)d_in[0];
  const int*   EI   = (const int*)d_in[1];
  const float* Wemb = (const float*)d_in[3];
  const float* bemb = (const float*)d_in[4];
  const float* gW1  = (const float*)d_in[5];
  const float* gb1  = (const float*)d_in[6];
  const float* gaw  = (const float*)d_in[7];
  const float* gab  = (const float*)d_in[8];
  const float* gW2  = (const float*)d_in[9];
  const float* gb2  = (const float*)d_in[10];
  const float* mW1  = (const float*)d_in[11];
  const float* mb1  = (const float*)d_in[12];
  const float* maw  = (const float*)d_in[13];
  const float* mab  = (const float*)d_in[14];
  const float* mW2  = (const float*)d_in[15];
  const float* mb2  = (const float*)d_in[16];
  const float* fW1  = (const float*)d_in[17];
  const float* fb1  = (const float*)d_in[18];
  const float* faw  = (const float*)d_in[19];
  const float* fab  = (const float*)d_in[20];
  const float* fW2  = (const float*)d_in[21];
  const float* fb2  = (const float*)d_in[22];

  unsigned short* p = (unsigned short*)d_ws;
  unsigned short* fW1t = p; p += 3 * H2 * DD;
  unsigned short* fW2t = p; p += 3 * H2 * DD;
  unsigned short* eh   = p; p += DD * DD;
  unsigned short* el   = p; p += DD * DD;
  unsigned short* g1h  = p; p += 2 * H2 * DD;
  unsigned short* g1l  = p; p += 2 * H2 * DD;
  unsigned short* g2h  = p; p += 2 * H2 * DD;
  unsigned short* g2l  = p; p += 2 * H2 * DD;
  unsigned short* m1h  = p; p += H2 * DD;
  unsigned short* m1l  = p; p += H2 * DD;
  unsigned short* m2h  = p; p += H2 * DD;
  unsigned short* m2l  = p; p += H2 * DD;
  unsigned short* gadj = p; p += NE;            // persisted CSR adj
  int* goffs = (int*)p;                          // persisted CSR offs (4B-aligned: even u16s)
  unsigned* repb = (unsigned*)(goffs + NG * (NPG + 1));
  float* esc = (float*)(repb + (size_t)NN * 64);
  float* gmm = esc + NE;
  float* smm = gmm + 2 * NG;
  float* out = (float*)d_out;

  k_wconv<<<(3 * H2 * DD + 255) / 256, 256, 0, stream>>>(
      Wemb, gW1, gW2, mW1, mW2, fW1, fW2,
      fW1t, fW2t, eh, el, g1h, g1l, g2h, g2l, m1h, m1l, m2h, m2l);
  k1_gnn_score<<<NG, 512, 0, stream>>>(x, EI, eh, el, bemb,
                                       g1h, g1l, gb1, gaw, gab, g2h, g2l, gb2,
                                       m1h, m1l, mb1, maw, mab, m2h, m2l, mb2,
                                       repb, esc, gmm, gadj, goffs);
  k2_minmax<<<1, 256, 0, stream>>>(gmm, smm);
  k3_select_fe<<<NG, 512, 0, stream>>>(EI, fW1t, fW2t, fb1, faw, fab, fb2, repb, esc, smm, out,
                                       gadj, goffs);
}